// Round 5
// baseline (701.914 us; speedup 1.0000x reference)
//
#include <hip/hip_runtime.h>
#include <math.h>

#define T_DIM 1000
#define C_DIM 500
#define U_DIM 100
#define PAD   16          // head/tail padding rows for P/PB (ring over-reads)
#define DEPTH 16          // scan prefetch ring depth
#define AROWS (T_DIM + 5) // A/Braw rows (loss ring reads to row T+4)
#define NEGINF (-INFINITY)

__device__ __forceinline__ float lse2f(float a, float b) {
    float m = fmaxf(a, b);
    if (m == NEGINF) return NEGINF;
    float mn = fminf(a, b);
    return m + __logf(1.0f + __expf(mn - m));
}

__device__ __forceinline__ float lse3f(float x1, float x2, float x3) {
    float m = fmaxf(fmaxf(x1, x2), x3);
    if (m == NEGINF) return NEGINF;
    return m + __logf(__expf(x1 - m) + __expf(x2 - m) + __expf(x3 - m));
}

// Bug-compatible replica of reference _log_sub_exp (incl. inf-substitution quirk).
__device__ __forceinline__ float log_sub_expf(float a, float b) {
    bool ia = isinf(a), ib = isinf(b);
    if (!ia && !ib) {
        float ans = b + __logf(__expf(a - b) - 1.0f);
        if (isinf(ans)) ans = -2001.0f + __logf(__expf(1.0f) - 1.0f);
        return ans;
    }
    if (!ia && ib) return a;
    return NEGINF;
}

// ---------------- forward scan: one wave64, compact-P, 16-deep ring ---------
__device__ __forceinline__ void fwd_scan2(const float* __restrict__ Pb,
                                          const float* __restrict__ PBb,
                                          const int* __restrict__ ysb,
                                          int hl, int yl,
                                          float* __restrict__ Ab)
{
    const int L = threadIdx.x & 63;
    const int s1 = 4 * L + 1, s3 = 4 * L + 3;
    const int u1 = 2 * L;
    const int lab1 = ysb[min(u1, U_DIM - 1)];
    const int lab3 = ysb[min(u1 + 1, U_DIM - 1)];
    const int labm = ysb[min(max(u1 - 1, 0), U_DIM - 1)];
    const bool skip1 = (s1 >= 3) && (lab1 != labm);
    const bool skip3 = (lab3 != lab1);
    const int ty = 2 * yl;
    const bool v0 = (4 * L     <= 200) && (4 * L     <= ty);
    const bool v1 = (s1        <= 200) && (s1        <= ty);
    const bool v2 = (4 * L + 2 <= 200) && (4 * L + 2 <= ty);
    const bool v3 = (s3        <= 200) && (s3        <= ty);
    const bool st = (L < 50);

    float a0 = (L == 0) ? 0.0f : NEGINF, a1 = NEGINF, a2 = NEGINF, a3 = NEGINF;

    // slot k consumed at t with t&15 == k, holds p row t
    float2 rl[DEPTH]; float rpb[DEPTH];
#pragma unroll
    for (int k = 0; k < DEPTH; ++k) {
        rl[k]  = ((const float2*)(Pb + (long)k * U_DIM))[L];
        rpb[k] = PBb[k];
    }
    auto step = [&](int t, int k) {
        float2 pl = rl[k]; float pbv = rpb[k];
        rl[k]  = ((const float2*)(Pb + (long)(t + DEPTH) * U_DIM))[L];
        rpb[k] = PBb[t + DEPTH];
        float p0 = v0 ? pbv : NEGINF;
        float p1 = v1 ? pl.x : NEGINF;
        float p2 = v2 ? pbv : NEGINF;
        float p3 = v3 ? pl.y : NEGINF;
        float am1 = __shfl_up(a3, 1, 64);
        if (L == 0) am1 = NEGINF;
        float n0 = p0 + lse2f(a0, am1);
        float n1 = p1 + lse3f(a1, a0, skip1 ? am1 : NEGINF);
        float n2 = p2 + lse2f(a2, a1);
        float n3 = p3 + lse3f(a3, a2, skip3 ? a1 : NEGINF);
        a0 = n0; a1 = n1; a2 = n2; a3 = n3;
        if (st) {
            bool live = (t < hl);
            ((float2*)(Ab + (size_t)t * U_DIM))[L] =
                make_float2(live ? n1 : NEGINF, live ? n3 : NEGINF);
        }
    };
    for (int tb = 0; tb < 992; tb += DEPTH) {
#pragma unroll
        for (int k = 0; k < DEPTH; ++k) step(tb + k, k);
    }
#pragma unroll
    for (int k = 0; k < 8; ++k) step(992 + k, k);
    // sentinel row T = -inf (consumed as a_next at t = T-1 in loss phase)
    if (st) ((float2*)(Ab + (size_t)T_DIM * U_DIM))[L] = make_float2(NEGINF, NEGINF);
}

// ---------------- backward scan: compact-P, stores raw b_l ------------------
__device__ __forceinline__ void bwd_scan2(const float* __restrict__ Pb,
                                          const float* __restrict__ PBb,
                                          const int* __restrict__ ysb,
                                          int hl, int yl,
                                          float* __restrict__ Bb)
{
    const int L = threadIdx.x & 63;
    const int s0 = 4 * L, s1 = 4 * L + 1, s2 = 4 * L + 2, s3 = 4 * L + 3;
    const int u1 = 2 * L;
    const int lab1 = ysb[min(u1, U_DIM - 1)];
    const int lab3 = ysb[min(u1 + 1, U_DIM - 1)];
    const int labn = ysb[min(u1 + 2, U_DIM - 1)];
    const bool skipA = (s1 < 199) && (lab3 != lab1);
    const bool skipB = (s3 < 199) && (labn != lab3);
    const int ty = 2 * yl;
    const bool v0 = (s0 <= 200) && (s0 <= ty);
    const bool v1 = (s1 <= 200) && (s1 <= ty);
    const bool v2 = (s2 <= 200) && (s2 <= ty);
    const bool v3 = (s3 <= 200) && (s3 <= ty);
    const bool st = (L < 50);
    const float f0 = (s0 == ty || s0 == ty - 1) ? 0.0f : NEGINF;
    const float f1 = (s1 == ty || s1 == ty - 1) ? 0.0f : NEGINF;
    const float f2 = (s2 == ty || s2 == ty - 1) ? 0.0f : NEGINF;
    const float f3 = (s3 == ty || s3 == ty - 1) ? 0.0f : NEGINF;

    float b0 = NEGINF, b1 = NEGINF, b2 = NEGINF, b3 = NEGINF;

    // slot k consumed at t with (999-t)&15==k, holds p row t+1
    float2 rl[DEPTH]; float rpb[DEPTH];
    rl[0] = make_float2(NEGINF, NEGINF); rpb[0] = NEGINF;   // row 1000 -> -inf
#pragma unroll
    for (int k = 1; k < DEPTH; ++k) {
        long row = T_DIM - k;
        rl[k]  = ((const float2*)(Pb + row * U_DIM))[L];
        rpb[k] = PBb[row];
    }
    auto step = [&](int t, int k) {
        float2 pl = rl[k]; float pbv = rpb[k];
        rl[k]  = ((const float2*)(Pb + (long)(t - (DEPTH - 1)) * U_DIM))[L];
        rpb[k] = PBb[t - (DEPTH - 1)];
        float ph0 = v0 ? pbv : NEGINF;   // p_ext[t+1]
        float ph1 = v1 ? pl.x : NEGINF;
        float ph2 = v2 ? pbv : NEGINF;
        float ph3 = v3 ? pl.y : NEGINF;
        float q0 = ph0 + b0, q1 = ph1 + b1, q2 = ph2 + b2, q3 = ph3 + b3;
        float qd0 = __shfl_down(q0, 1, 64);
        float qd1 = __shfl_down(q1, 1, 64);
        if (L == 63) { qd0 = NEGINF; qd1 = NEGINF; }
        float n0 = lse2f(q0, q1);
        float n1 = lse3f(q1, q2, skipA ? q3 : NEGINF);
        float n2 = lse2f(q2, q3);
        float n3 = lse3f(q3, qd0, skipB ? qd1 : NEGINF);
        bool fin = (t == hl - 1);
        b0 = fin ? f0 : n0;
        b1 = fin ? f1 : n1;
        b2 = fin ? f2 : n2;
        b3 = fin ? f3 : n3;
        if (st)
            ((float2*)(Bb + (size_t)t * U_DIM))[L] = make_float2(b1, b3);
    };
    for (int ob = 0; ob < 992; ob += DEPTH) {
#pragma unroll
        for (int k = 0; k < DEPTH; ++k) step(T_DIM - 1 - ob - k, k);
    }
#pragma unroll
    for (int k = 0; k < 8; ++k) step(7 - k, k);
}

// ---- mega kernel: in-kernel gather + concurrent scans + 8-way loss ---------
extern "C" __global__ void __launch_bounds__(1024)
brctc_mega(const float* __restrict__ nnet, const int* __restrict__ ys,
           const int* __restrict__ hlens, const int* __restrict__ ylens,
           float* __restrict__ P, float* __restrict__ PB,
           float* __restrict__ A, float* __restrict__ Braw,
           float* __restrict__ out)
{
    const int b = blockIdx.x;
    const int tid = threadIdx.x;
    const int hl = hlens[b], yl = ylens[b];
    const size_t TP = T_DIM + 2 * PAD;
    float* Pb  = P  + ((size_t)b * TP + PAD) * U_DIM;
    float* PBb = PB + (size_t)b * TP + PAD;
    const int* ysb = ys + b * U_DIM;
    float* Ab = A    + (size_t)b * AROWS * U_DIM;
    float* Bb = Braw + (size_t)b * AROWS * U_DIM;

    __shared__ int sl[U_DIM];
    __shared__ float shm[8][U_DIM], shs[8][U_DIM], shlu[U_DIM];

    if (tid < U_DIM) sl[tid] = ysb[tid];
    __syncthreads();

    // ---- phase 0: gather compact P (thread t owns row t; stays in local L2)
    if (tid < T_DIM) {
        const float* row = nnet + ((size_t)b * T_DIM + tid) * C_DIM;
        float* Pr = Pb + (size_t)tid * U_DIM;
#pragma unroll 5
        for (int u = 0; u < U_DIM; ++u) Pr[u] = row[sl[u]];
        PBb[tid] = row[0];
    }
    __syncthreads();

    // ---- phase 1: concurrent forward / backward scans (bit-exact, wave each)
    const int wid = tid >> 6;
    if (wid == 0)      fwd_scan2(Pb, PBb, ysb, hl, yl, Ab);
    else if (wid == 1) bwd_scan2(Pb, PBb, ysb, hl, yl, Bb);
    __syncthreads();

    // ---- phase 2: loss, 8 chunks x 125 t, 4-deep rings, online LSE ---------
    {
        const int u = tid & 127;
        const int c = tid >> 7;               // 0..7
        if (u < U_DIM) {
            const bool valu = (u < yl);       // p_l valid mask (s=2u+1 <= 2yl)
            const float inv_hl = 1.0f / (float)hl;
            const int t0 = 125 * c;
            float a_t    = Ab[(size_t)t0 * U_DIM + u];
            float braw_t = Bb[(size_t)t0 * U_DIM + u];
            // slot for row r is (r - t0 - 1) & 3; consume row t+1 at slot k&3
            float ra[4], rbw[4], rp[4];
#pragma unroll
            for (int d = 0; d < 4; ++d) {
                long row = t0 + 1 + d;
                ra[d]  = Ab[row * U_DIM + u];
                rbw[d] = Bb[row * U_DIM + u];
                rp[d]  = valu ? Pb[row * U_DIM + u] : NEGINF;
            }
            float m = NEGINF, ssum = 0.0f;
            for (int k = 0; k < 125; ++k) {
                const int t = t0 + k;
                const int slot = k & 3;
                float a_nx = ra[slot], br_nx = rbw[slot], p_nx = rp[slot];
                long row = t + 5;             // refill same slot
                ra[slot]  = Ab[row * U_DIM + u];
                rbw[slot] = Bb[row * U_DIM + u];
                rp[slot]  = valu ? Pb[row * U_DIM + u] : NEGINF;
                float bl   = (a_t  == NEGINF) ? NEGINF : braw_t;
                float term = (a_nx == NEGINF) ? NEGINF : (br_nx + p_nx);
                float bp = log_sub_expf(bl, term);
                float x = a_t + bp - 0.1f * (float)t * inv_hl;
                if (x != NEGINF) {
                    float nm = fmaxf(m, x);
                    ssum = ssum * __expf(m - nm) + __expf(x - nm);
                    m = nm;
                }
                a_t = a_nx; braw_t = br_nx;
            }
            shm[c][u] = m; shs[c][u] = ssum;
        }
    }
    __syncthreads();
    if (tid < U_DIM) {
        float M = NEGINF;
#pragma unroll
        for (int c = 0; c < 8; ++c) M = fmaxf(M, shm[c][tid]);
        float lu = NEGINF;
        if (M != NEGINF) {
            float s = 0.0f;
#pragma unroll
            for (int c = 0; c < 8; ++c) {
                float mc = shm[c][tid];
                if (mc != NEGINF) s += shs[c][tid] * __expf(mc - M);
            }
            lu = M + __logf(s);
        }
        shlu[tid] = lu;
    }
    __syncthreads();
    if (tid == 0) {
        int cnt = 0;
        for (int u = 0; u < U_DIM; ++u) cnt += (shlu[u] != NEGINF) ? 1 : 0;
        int last = cnt - 1;
        last = last < 0 ? 0 : (last > U_DIM - 1 ? U_DIM - 1 : last);
        out[b] = -shlu[last];
    }
}

// =================== fallback (small ws): round-1-style direct path =========
__device__ __forceinline__ void fwd_scan_direct(const float* __restrict__ base,
                                                const int* __restrict__ ysb,
                                                int hl, int yl,
                                                float* __restrict__ A)
{
    const int L = threadIdx.x & 63;
    const int s1 = 4 * L + 1, s3 = 4 * L + 3;
    const int u1 = 2 * L, u3 = 2 * L + 1;
    const int lab1 = ysb[min(u1, U_DIM - 1)];
    const int lab3 = ysb[min(u3, U_DIM - 1)];
    const int labm = ysb[min(max(u1 - 1, 0), U_DIM - 1)];
    const bool skip1 = (s1 >= 3) && (lab1 != labm);
    const bool skip3 = (lab3 != lab1);
    const int ty = 2 * yl;
    const bool v0 = (4 * L     <= 200) && (4 * L     <= ty);
    const bool v1 = (s1        <= 200) && (s1        <= ty);
    const bool v2 = (4 * L + 2 <= 200) && (4 * L + 2 <= ty);
    const bool v3 = (s3        <= 200) && (s3        <= ty);
    const bool st = (L < 50);
    float a0 = (L == 0) ? 0.0f : NEGINF, a1 = NEGINF, a2 = NEGINF, a3 = NEGINF;
    float rb[4], r1[4], r3[4];
#pragma unroll
    for (int k = 0; k < 4; ++k) {
        const float* r = base + (size_t)k * C_DIM;
        rb[k] = r[0]; r1[k] = r[lab1]; r3[k] = r[lab3];
    }
    for (int tb = 0; tb < T_DIM; tb += 4) {
#pragma unroll
        for (int k = 0; k < 4; ++k) {
            const int t = tb + k;
            float p0 = v0 ? rb[k] : NEGINF;
            float p1 = v1 ? r1[k] : NEGINF;
            float p2 = v2 ? rb[k] : NEGINF;
            float p3 = v3 ? r3[k] : NEGINF;
            if (t + 4 < T_DIM) {
                const float* r = base + (size_t)(t + 4) * C_DIM;
                rb[k] = r[0]; r1[k] = r[lab1]; r3[k] = r[lab3];
            }
            float am1 = __shfl_up(a3, 1, 64);
            if (L == 0) am1 = NEGINF;
            float n0 = p0 + lse2f(a0, am1);
            float n1 = p1 + lse3f(a1, a0, skip1 ? am1 : NEGINF);
            float n2 = p2 + lse2f(a2, a1);
            float n3 = p3 + lse3f(a3, a2, skip3 ? a1 : NEGINF);
            a0 = n0; a1 = n1; a2 = n2; a3 = n3;
            if (st) {
                float* Ar = A + (size_t)t * U_DIM;
                bool live = (t < hl);
                Ar[u1] = live ? n1 : NEGINF;
                Ar[u3] = live ? n3 : NEGINF;
            }
        }
    }
}

extern "C" __global__ void __launch_bounds__(64)
brctc_fwd64(const float* __restrict__ nnet, const int* __restrict__ ys,
            const int* __restrict__ hlens, const int* __restrict__ ylens, float* A)
{
    const int b = blockIdx.x;
    fwd_scan_direct(nnet + (size_t)b * T_DIM * C_DIM, ys + b * U_DIM,
                    hlens[b], ylens[b], A + (size_t)b * T_DIM * U_DIM);
}

extern "C" __global__ void __launch_bounds__(64)
brctc_bwd64(const float* __restrict__ nnet, const int* __restrict__ ys,
            const int* __restrict__ hlens, const int* __restrict__ ylens,
            const float* __restrict__ A, float* out)
{
    const int b = blockIdx.x;
    const int L = threadIdx.x & 63;
    const int s0 = 4 * L, s1 = 4 * L + 1, s2 = 4 * L + 2, s3 = 4 * L + 3;
    const int u1 = 2 * L, u3 = 2 * L + 1;
    const int hl = hlens[b], yl = ylens[b];
    const float* base = nnet + (size_t)b * T_DIM * C_DIM;
    const int* ysb = ys + b * U_DIM;
    const float* Ab = A + (size_t)b * T_DIM * U_DIM;
    const int lab1 = ysb[min(u1, U_DIM - 1)];
    const int lab3 = ysb[min(u3, U_DIM - 1)];
    const int labn = ysb[min(u3 + 1, U_DIM - 1)];
    const bool skipA = (s1 < 199) && (lab3 != lab1);
    const bool skipB = (s3 < 199) && (labn != lab3);
    const int ty = 2 * yl;
    const bool v0 = (s0 <= 200) && (s0 <= ty);
    const bool v1 = (s1 <= 200) && (s1 <= ty);
    const bool v2 = (s2 <= 200) && (s2 <= ty);
    const bool v3 = (s3 <= 200) && (s3 <= ty);
    const bool st = (L < 50);
    const float f0 = (s0 == ty || s0 == ty - 1) ? 0.0f : NEGINF;
    const float f1 = (s1 == ty || s1 == ty - 1) ? 0.0f : NEGINF;
    const float f2 = (s2 == ty || s2 == ty - 1) ? 0.0f : NEGINF;
    const float f3 = (s3 == ty || s3 == ty - 1) ? 0.0f : NEGINF;
    const float inv_hl = 1.0f / (float)hl;

    float b0 = NEGINF, b1 = NEGINF, b2 = NEGINF, b3 = NEGINF;
    float prev1 = NEGINF, prev3 = NEGINF;
    float m1 = NEGINF, ss1 = 0.0f, m3 = NEGINF, ss3 = 0.0f;

    float rb[4], r1[4], r3[4], ra1[4], ra3[4];
    rb[0] = NEGINF; r1[0] = NEGINF; r3[0] = NEGINF;
#pragma unroll
    for (int k = 1; k < 4; ++k) {
        const float* r = base + (size_t)(T_DIM - k) * C_DIM;
        rb[k] = r[0]; r1[k] = r[lab1]; r3[k] = r[lab3];
    }
#pragma unroll
    for (int k = 0; k < 4; ++k) {
        if (st) {
            ra1[k] = Ab[(size_t)(T_DIM - 1 - k) * U_DIM + u1];
            ra3[k] = Ab[(size_t)(T_DIM - 1 - k) * U_DIM + u3];
        } else { ra1[k] = NEGINF; ra3[k] = NEGINF; }
    }
    for (int ob = 0; ob < T_DIM; ob += 4) {
#pragma unroll
        for (int k = 0; k < 4; ++k) {
            const int t = T_DIM - 1 - ob - k;
            float ph0 = v0 ? rb[k] : NEGINF;
            float ph1 = v1 ? r1[k] : NEGINF;
            float ph2 = v2 ? rb[k] : NEGINF;
            float ph3 = v3 ? r3[k] : NEGINF;
            float a1v = ra1[k], a3v = ra3[k];
            if (t - 3 >= 1) {
                const float* r = base + (size_t)(t - 3) * C_DIM;
                rb[k] = r[0]; r1[k] = r[lab1]; r3[k] = r[lab3];
            }
            if (t - 4 >= 0 && st) {
                ra1[k] = Ab[(size_t)(t - 4) * U_DIM + u1];
                ra3[k] = Ab[(size_t)(t - 4) * U_DIM + u3];
            }
            float q0 = ph0 + b0, q1 = ph1 + b1, q2 = ph2 + b2, q3 = ph3 + b3;
            float qd0 = __shfl_down(q0, 1, 64);
            float qd1 = __shfl_down(q1, 1, 64);
            if (L == 63) { qd0 = NEGINF; qd1 = NEGINF; }
            float n0 = lse2f(q0, q1);
            float n1 = lse3f(q1, q2, skipA ? q3 : NEGINF);
            float n2 = lse2f(q2, q3);
            float n3 = lse3f(q3, qd0, skipB ? qd1 : NEGINF);
            bool fin = (t == hl - 1);
            b0 = fin ? f0 : n0;
            b1 = fin ? f1 : n1;
            b2 = fin ? f2 : n2;
            b3 = fin ? f3 : n3;
            if (st) {
                float risk = 0.1f * (float)t * inv_hl;
                float bl1 = (a1v == NEGINF) ? NEGINF : b1;
                float bp1 = log_sub_expf(bl1, prev1 + ph1);
                float x1 = a1v + bp1 - risk;
                if (x1 != NEGINF) {
                    float nm = fmaxf(m1, x1);
                    ss1 = ss1 * __expf(m1 - nm) + __expf(x1 - nm);
                    m1 = nm;
                }
                prev1 = bl1;
                float bl3 = (a3v == NEGINF) ? NEGINF : b3;
                float bp3 = log_sub_expf(bl3, prev3 + ph3);
                float x3 = a3v + bp3 - risk;
                if (x3 != NEGINF) {
                    float nm = fmaxf(m3, x3);
                    ss3 = ss3 * __expf(m3 - nm) + __expf(x3 - nm);
                    m3 = nm;
                }
                prev3 = bl3;
            }
        }
    }
    __shared__ float shlu[U_DIM];
    if (st) {
        shlu[u1] = (m1 == NEGINF) ? NEGINF : (m1 + __logf(ss1));
        shlu[u3] = (m3 == NEGINF) ? NEGINF : (m3 + __logf(ss3));
    }
    __syncthreads();
    if (threadIdx.x == 0) {
        int cnt = 0;
        for (int u = 0; u < U_DIM; ++u) cnt += (shlu[u] != NEGINF) ? 1 : 0;
        int last = cnt - 1;
        last = last < 0 ? 0 : (last > U_DIM - 1 ? U_DIM - 1 : last);
        out[b] = -shlu[last];
    }
}

extern "C" void kernel_launch(void* const* d_in, const int* in_sizes, int n_in,
                              void* d_out, int out_size, void* d_ws, size_t ws_size,
                              hipStream_t stream) {
    const float* nnet  = (const float*)d_in[0];
    const int*   ys    = (const int*)d_in[1];
    const int*   hlens = (const int*)d_in[2];
    const int*   ylens = (const int*)d_in[3];
    float*       outp  = (float*)d_out;
    const int B = in_sizes[2];
    const size_t TP = T_DIM + 2 * PAD;
    const size_t szP  = (size_t)B * TP * U_DIM;
    const size_t szPB = (size_t)B * TP;
    const size_t szA  = (size_t)B * AROWS * U_DIM;
    const size_t need = (szP + szPB + 2 * szA) * sizeof(float);

    if (ws_size >= need) {
        float* P    = (float*)d_ws;
        float* PB   = P + szP;
        float* A    = PB + szPB;
        float* Braw = A + szA;
        brctc_mega<<<B, 1024, 0, stream>>>(nnet, ys, hlens, ylens,
                                           P, PB, A, Braw, outp);
    } else {
        float* A = (float*)d_ws;
        brctc_fwd64<<<B, 64, 0, stream>>>(nnet, ys, hlens, ylens, A);
        brctc_bwd64<<<B, 64, 0, stream>>>(nnet, ys, hlens, ylens, A, outp);
    }
}

// Round 6
// 613.226 us; speedup vs baseline: 1.1446x; 1.1446x over previous
//
#include <hip/hip_runtime.h>
#include <math.h>

#define T_DIM 1000
#define C_DIM 500
#define U_DIM 100
#define PAD   16          // head/tail padding rows for P/PB (ring over-reads)
#define DEPTH 16          // scan prefetch ring depth
#define AROWS (T_DIM + 5) // A/Braw rows (loss ring reads to row T+4)
#define NEGINF (-INFINITY)

__device__ __forceinline__ float lse2f(float a, float b) {
    float m = fmaxf(a, b);
    if (m == NEGINF) return NEGINF;
    float mn = fminf(a, b);
    return m + __logf(1.0f + __expf(mn - m));
}

__device__ __forceinline__ float lse3f(float x1, float x2, float x3) {
    float m = fmaxf(fmaxf(x1, x2), x3);
    if (m == NEGINF) return NEGINF;
    return m + __logf(__expf(x1 - m) + __expf(x2 - m) + __expf(x3 - m));
}

// Bug-compatible replica of reference _log_sub_exp (incl. inf-substitution quirk).
__device__ __forceinline__ float log_sub_expf(float a, float b) {
    bool ia = isinf(a), ib = isinf(b);
    if (!ia && !ib) {
        float ans = b + __logf(__expf(a - b) - 1.0f);
        if (isinf(ans)) ans = -2001.0f + __logf(__expf(1.0f) - 1.0f);
        return ans;
    }
    if (!ia && ib) return a;
    return NEGINF;
}

// DPP lane shifts (VALU, ~4cy — replaces ds_bpermute __shfl ~120cy on the chain)
__device__ __forceinline__ float dpp_shr1(float x) {  // lane L <- lane L-1; lane0 <- -inf
    int r = __builtin_amdgcn_update_dpp(__float_as_int(NEGINF), __float_as_int(x),
                                        0x138, 0xF, 0xF, false);  // wave_shr:1
    return __int_as_float(r);
}
__device__ __forceinline__ float dpp_shl1(float x) {  // lane L <- lane L+1; lane63 <- -inf
    int r = __builtin_amdgcn_update_dpp(__float_as_int(NEGINF), __float_as_int(x),
                                        0x130, 0xF, 0xF, false);  // wave_shl:1
    return __int_as_float(r);
}

// ---------------- forward scan: one wave64, compact-P, 16-deep ring ---------
__device__ __forceinline__ void fwd_scan3(const float* __restrict__ Pb,
                                          const float* __restrict__ PBb,
                                          const int* __restrict__ ysb,
                                          int hl, int yl,
                                          float* __restrict__ Ab)
{
    const int L = threadIdx.x & 63;
    const int s1 = 4 * L + 1, s3 = 4 * L + 3;
    const int u1 = 2 * L;
    const int lab1 = ysb[min(u1, U_DIM - 1)];
    const int lab3 = ysb[min(u1 + 1, U_DIM - 1)];
    const int labm = ysb[min(max(u1 - 1, 0), U_DIM - 1)];
    const bool skip1 = (s1 >= 3) && (lab1 != labm);
    const bool skip3 = (lab3 != lab1);
    const int ty = 2 * yl;
    const bool v0 = (4 * L     <= 200) && (4 * L     <= ty);
    const bool v1 = (s1        <= 200) && (s1        <= ty);
    const bool v2 = (4 * L + 2 <= 200) && (4 * L + 2 <= ty);
    const bool v3 = (s3        <= 200) && (s3        <= ty);
    const bool st = (L < 50);

    float a0 = (L == 0) ? 0.0f : NEGINF, a1 = NEGINF, a2 = NEGINF, a3 = NEGINF;

    // slot k consumed at t with t%16 == k, holds p row t
    float2 rl[DEPTH]; float rpb[DEPTH];
#pragma unroll
    for (int k = 0; k < DEPTH; ++k) {
        rl[k]  = ((const float2*)(Pb + (long)k * U_DIM))[L];
        rpb[k] = PBb[k];
    }
    auto step = [&](int t, int k) {
        float2 pl = rl[k]; float pbv = rpb[k];
        rl[k]  = ((const float2*)(Pb + (long)(t + DEPTH) * U_DIM))[L];
        rpb[k] = PBb[t + DEPTH];
        float p0 = v0 ? pbv : NEGINF;
        float p1 = v1 ? pl.x : NEGINF;
        float p2 = v2 ? pbv : NEGINF;
        float p3 = v3 ? pl.y : NEGINF;
        float am1 = dpp_shr1(a3);            // a[4L-1], lane0 -> -inf
        float n0 = p0 + lse2f(a0, am1);
        float n1 = p1 + lse3f(a1, a0, skip1 ? am1 : NEGINF);
        float n2 = p2 + lse2f(a2, a1);
        float n3 = p3 + lse3f(a3, a2, skip3 ? a1 : NEGINF);
        a0 = n0; a1 = n1; a2 = n2; a3 = n3;
        if (st)
            ((float2*)(Ab + (size_t)t * U_DIM))[L] = make_float2(n1, n3);
    };
    int tb = 0;
    for (; tb + DEPTH <= hl; tb += DEPTH) {
#pragma unroll
        for (int k = 0; k < DEPTH; ++k) step(tb + k, k);
    }
    for (int k = 0; tb < hl; ++tb, ++k) step(tb, k);
    // rows [hl, AROWS) filled with -inf by the filler waves
}

// ---------------- backward scan: starts at t=hl-1 (beta_fin), stores raw b_l
__device__ __forceinline__ void bwd_scan3(const float* __restrict__ Pb,
                                          const float* __restrict__ PBb,
                                          const int* __restrict__ ysb,
                                          int hl, int yl,
                                          float* __restrict__ Bb)
{
    const int L = threadIdx.x & 63;
    const int s0 = 4 * L, s1 = 4 * L + 1, s2 = 4 * L + 2, s3 = 4 * L + 3;
    const int u1 = 2 * L;
    const int lab1 = ysb[min(u1, U_DIM - 1)];
    const int lab3 = ysb[min(u1 + 1, U_DIM - 1)];
    const int labn = ysb[min(u1 + 2, U_DIM - 1)];
    const bool skipA = (s1 < 199) && (lab3 != lab1);
    const bool skipB = (s3 < 199) && (labn != lab3);
    const int ty = 2 * yl;
    const bool v0 = (s0 <= 200) && (s0 <= ty);
    const bool v1 = (s1 <= 200) && (s1 <= ty);
    const bool v2 = (s2 <= 200) && (s2 <= ty);
    const bool v3 = (s3 <= 200) && (s3 <= ty);
    const bool st = (L < 50);
    const float f0 = (s0 == ty || s0 == ty - 1) ? 0.0f : NEGINF;
    const float f1 = (s1 == ty || s1 == ty - 1) ? 0.0f : NEGINF;
    const float f2 = (s2 == ty || s2 == ty - 1) ? 0.0f : NEGINF;
    const float f3 = (s3 == ty || s3 == ty - 1) ? 0.0f : NEGINF;

    // row hl-1 is beta_fin; carry starts from it — no per-step fin select
    float b0 = f0, b1 = f1, b2 = f2, b3 = f3;
    if (st) ((float2*)(Bb + (size_t)(hl - 1) * U_DIM))[L] = make_float2(f1, f3);

    // slot k initially holds p row (hl-1-k); consumed at t with row t+1
    float2 rl[DEPTH]; float rpb[DEPTH];
#pragma unroll
    for (int k = 0; k < DEPTH; ++k) {
        long row = (long)(hl - 1 - k);
        rl[k]  = ((const float2*)(Pb + row * U_DIM))[L];
        rpb[k] = PBb[row];
    }
    auto step = [&](int t, int k) {
        float2 pl = rl[k]; float pbv = rpb[k];
        rl[k]  = ((const float2*)(Pb + (long)(t - (DEPTH - 1)) * U_DIM))[L];
        rpb[k] = PBb[t - (DEPTH - 1)];
        float ph0 = v0 ? pbv : NEGINF;   // p_ext[t+1]
        float ph1 = v1 ? pl.x : NEGINF;
        float ph2 = v2 ? pbv : NEGINF;
        float ph3 = v3 ? pl.y : NEGINF;
        float q0 = ph0 + b0, q1 = ph1 + b1, q2 = ph2 + b2, q3 = ph3 + b3;
        float qd0 = dpp_shl1(q0);        // q[4L+4], lane63 -> -inf
        float qd1 = dpp_shl1(q1);        // q[4L+5]
        float n0 = lse2f(q0, q1);
        float n1 = lse3f(q1, q2, skipA ? q3 : NEGINF);
        float n2 = lse2f(q2, q3);
        float n3 = lse3f(q3, qd0, skipB ? qd1 : NEGINF);
        b0 = n0; b1 = n1; b2 = n2; b3 = n3;
        if (st)
            ((float2*)(Bb + (size_t)t * U_DIM))[L] = make_float2(n1, n3);
    };
    const int total = hl - 1;            // steps t = hl-2 .. 0
    int t = hl - 2, j = 0;
    for (; j + DEPTH <= total; j += DEPTH, t -= DEPTH) {
#pragma unroll
        for (int k = 0; k < DEPTH; ++k) step(t - k, k);
    }
    for (int k = 0; j < total; ++j, ++k) step(t - k, k);
}

// ---- mega kernel: LDS-staged gather + DPP scans + filler waves + 8-way loss
extern "C" __global__ void __launch_bounds__(1024)
brctc_mega(const float* __restrict__ nnet, const int* __restrict__ ys,
           const int* __restrict__ hlens, const int* __restrict__ ylens,
           float* __restrict__ P, float* __restrict__ PB,
           float* __restrict__ A, float* __restrict__ Braw,
           float* __restrict__ out)
{
    const int b = blockIdx.x;
    const int tid = threadIdx.x;
    const int w = tid >> 6, L = tid & 63;
    const int hl = hlens[b], yl = ylens[b];
    const size_t TP = T_DIM + 2 * PAD;
    float* Pb  = P  + ((size_t)b * TP + PAD) * U_DIM;
    float* PBb = PB + (size_t)b * TP + PAD;
    const int* ysb = ys + b * U_DIM;
    float* Ab = A    + (size_t)b * AROWS * U_DIM;
    float* Bb = Braw + (size_t)b * AROWS * U_DIM;

    __shared__ int sl[U_DIM];
    __shared__ float srow[16][512];      // 2KB staging slab per wave
    __shared__ float shm[8][U_DIM], shs[8][U_DIM], shlu[U_DIM];

    if (tid < U_DIM) sl[tid] = ysb[tid];
    // zero the pad rows (ring over-reads land here; must be non-NaN)
    for (int i = tid; i < 2 * PAD * U_DIM; i += 1024) {
        int r = i / U_DIM, u = i % U_DIM;
        long row = (r < PAD) ? (long)(r - PAD) : (long)(T_DIM + r - PAD);
        Pb[row * U_DIM + u] = 0.0f;
    }
    if (tid < 2 * PAD) {
        long row = (tid < PAD) ? (long)(tid - PAD) : (long)(T_DIM + tid - PAD);
        PBb[row] = 0.0f;
    }
    __syncthreads();

    // ---- phase 0: gather — wave w stages row coalesced into LDS, scatters out
    {
        float cur[8], nxt[8];
        const float* r0 = nnet + ((size_t)b * T_DIM + w) * C_DIM;
#pragma unroll
        for (int i = 0; i < 8; ++i) {
            int idx = L + 64 * i;
            cur[i] = (idx < C_DIM) ? r0[idx] : 0.0f;
        }
        for (int r = w; r < T_DIM; r += 16) {
            if (r + 16 < T_DIM) {
                const float* rw = nnet + ((size_t)b * T_DIM + r + 16) * C_DIM;
#pragma unroll
                for (int i = 0; i < 8; ++i) {
                    int idx = L + 64 * i;
                    nxt[i] = (idx < C_DIM) ? rw[idx] : 0.0f;
                }
            } else {
#pragma unroll
                for (int i = 0; i < 8; ++i) nxt[i] = 0.0f;
            }
#pragma unroll
            for (int i = 0; i < 8; ++i) {
                int idx = L + 64 * i;
                if (idx < C_DIM) srow[w][idx] = cur[i];
            }
            __builtin_amdgcn_wave_barrier();   // keep write->read order (DS in-order/wave)
            float* Pr = Pb + (size_t)r * U_DIM;
#pragma unroll
            for (int uu = 0; uu < 2; ++uu) {
                int u = L + 64 * uu;
                if (u < U_DIM) Pr[u] = srow[w][sl[u]];
            }
            if (L == 0) PBb[r] = srow[w][0];
            __builtin_amdgcn_wave_barrier();
#pragma unroll
            for (int i = 0; i < 8; ++i) cur[i] = nxt[i];
        }
    }
    __syncthreads();

    // ---- phase 1: DPP scans on waves 0/1; waves 2..15 fill dead rows -------
    if (w == 0)      fwd_scan3(Pb, PBb, ysb, hl, yl, Ab);
    else if (w == 1) bwd_scan3(Pb, PBb, ysb, hl, yl, Bb);
    else {
        const int n = (AROWS - hl) * U_DIM;   // rows [hl, AROWS) of A and Braw
        for (int i = (w - 2) * 64 + L; i < n; i += 14 * 64) {
            int r = hl + i / U_DIM, u = i % U_DIM;
            Ab[(size_t)r * U_DIM + u] = NEGINF;
            Bb[(size_t)r * U_DIM + u] = NEGINF;
        }
    }
    __syncthreads();

    // ---- phase 2: loss, 8 chunks x 125 t, 4-deep rings, online LSE ---------
    {
        const int u = tid & 127;
        const int c = tid >> 7;               // 0..7
        if (u < U_DIM) {
            const bool valu = (u < yl);       // p_l valid mask (s=2u+1 <= 2yl)
            const float inv_hl = 1.0f / (float)hl;
            const int t0 = 125 * c;
            const int tcnt = min(125, max(0, hl - t0));  // t >= hl contribute nothing
            float a_t    = Ab[(size_t)t0 * U_DIM + u];
            float braw_t = Bb[(size_t)t0 * U_DIM + u];
            float ra[4], rbw[4], rp[4];
#pragma unroll
            for (int d = 0; d < 4; ++d) {
                long row = t0 + 1 + d;
                ra[d]  = Ab[row * U_DIM + u];
                rbw[d] = Bb[row * U_DIM + u];
                rp[d]  = valu ? Pb[row * U_DIM + u] : NEGINF;
            }
            float m = NEGINF, ssum = 0.0f;
            for (int k = 0; k < tcnt; ++k) {
                const int t = t0 + k;
                const int slot = k & 3;
                float a_nx = ra[slot], br_nx = rbw[slot], p_nx = rp[slot];
                long row = t + 5;             // refill same slot
                ra[slot]  = Ab[row * U_DIM + u];
                rbw[slot] = Bb[row * U_DIM + u];
                rp[slot]  = valu ? Pb[row * U_DIM + u] : NEGINF;
                float bl   = (a_t  == NEGINF) ? NEGINF : braw_t;
                float term = (a_nx == NEGINF) ? NEGINF : (br_nx + p_nx);
                float bp = log_sub_expf(bl, term);
                float x = a_t + bp - 0.1f * (float)t * inv_hl;
                if (x != NEGINF) {
                    float nm = fmaxf(m, x);
                    ssum = ssum * __expf(m - nm) + __expf(x - nm);
                    m = nm;
                }
                a_t = a_nx; braw_t = br_nx;
            }
            shm[c][u] = m; shs[c][u] = ssum;
        }
    }
    __syncthreads();
    if (tid < U_DIM) {
        float M = NEGINF;
#pragma unroll
        for (int c = 0; c < 8; ++c) M = fmaxf(M, shm[c][tid]);
        float lu = NEGINF;
        if (M != NEGINF) {
            float s = 0.0f;
#pragma unroll
            for (int c = 0; c < 8; ++c) {
                float mc = shm[c][tid];
                if (mc != NEGINF) s += shs[c][tid] * __expf(mc - M);
            }
            lu = M + __logf(s);
        }
        shlu[tid] = lu;
    }
    __syncthreads();
    if (tid == 0) {
        int cnt = 0;
        for (int u = 0; u < U_DIM; ++u) cnt += (shlu[u] != NEGINF) ? 1 : 0;
        int last = cnt - 1;
        last = last < 0 ? 0 : (last > U_DIM - 1 ? U_DIM - 1 : last);
        out[b] = -shlu[last];
    }
}

// =================== fallback (small ws): round-1-style direct path =========
__device__ __forceinline__ void fwd_scan_direct(const float* __restrict__ base,
                                                const int* __restrict__ ysb,
                                                int hl, int yl,
                                                float* __restrict__ A)
{
    const int L = threadIdx.x & 63;
    const int s1 = 4 * L + 1, s3 = 4 * L + 3;
    const int u1 = 2 * L, u3 = 2 * L + 1;
    const int lab1 = ysb[min(u1, U_DIM - 1)];
    const int lab3 = ysb[min(u3, U_DIM - 1)];
    const int labm = ysb[min(max(u1 - 1, 0), U_DIM - 1)];
    const bool skip1 = (s1 >= 3) && (lab1 != labm);
    const bool skip3 = (lab3 != lab1);
    const int ty = 2 * yl;
    const bool v0 = (4 * L     <= 200) && (4 * L     <= ty);
    const bool v1 = (s1        <= 200) && (s1        <= ty);
    const bool v2 = (4 * L + 2 <= 200) && (4 * L + 2 <= ty);
    const bool v3 = (s3        <= 200) && (s3        <= ty);
    const bool st = (L < 50);
    float a0 = (L == 0) ? 0.0f : NEGINF, a1 = NEGINF, a2 = NEGINF, a3 = NEGINF;
    float rb[4], r1[4], r3[4];
#pragma unroll
    for (int k = 0; k < 4; ++k) {
        const float* r = base + (size_t)k * C_DIM;
        rb[k] = r[0]; r1[k] = r[lab1]; r3[k] = r[lab3];
    }
    for (int tb = 0; tb < T_DIM; tb += 4) {
#pragma unroll
        for (int k = 0; k < 4; ++k) {
            const int t = tb + k;
            float p0 = v0 ? rb[k] : NEGINF;
            float p1 = v1 ? r1[k] : NEGINF;
            float p2 = v2 ? rb[k] : NEGINF;
            float p3 = v3 ? r3[k] : NEGINF;
            if (t + 4 < T_DIM) {
                const float* r = base + (size_t)(t + 4) * C_DIM;
                rb[k] = r[0]; r1[k] = r[lab1]; r3[k] = r[lab3];
            }
            float am1 = __shfl_up(a3, 1, 64);
            if (L == 0) am1 = NEGINF;
            float n0 = p0 + lse2f(a0, am1);
            float n1 = p1 + lse3f(a1, a0, skip1 ? am1 : NEGINF);
            float n2 = p2 + lse2f(a2, a1);
            float n3 = p3 + lse3f(a3, a2, skip3 ? a1 : NEGINF);
            a0 = n0; a1 = n1; a2 = n2; a3 = n3;
            if (st) {
                float* Ar = A + (size_t)t * U_DIM;
                bool live = (t < hl);
                Ar[u1] = live ? n1 : NEGINF;
                Ar[u3] = live ? n3 : NEGINF;
            }
        }
    }
}

extern "C" __global__ void __launch_bounds__(64)
brctc_fwd64(const float* __restrict__ nnet, const int* __restrict__ ys,
            const int* __restrict__ hlens, const int* __restrict__ ylens, float* A)
{
    const int b = blockIdx.x;
    fwd_scan_direct(nnet + (size_t)b * T_DIM * C_DIM, ys + b * U_DIM,
                    hlens[b], ylens[b], A + (size_t)b * T_DIM * U_DIM);
}

extern "C" __global__ void __launch_bounds__(64)
brctc_bwd64(const float* __restrict__ nnet, const int* __restrict__ ys,
            const int* __restrict__ hlens, const int* __restrict__ ylens,
            const float* __restrict__ A, float* out)
{
    const int b = blockIdx.x;
    const int L = threadIdx.x & 63;
    const int s0 = 4 * L, s1 = 4 * L + 1, s2 = 4 * L + 2, s3 = 4 * L + 3;
    const int u1 = 2 * L, u3 = 2 * L + 1;
    const int hl = hlens[b], yl = ylens[b];
    const float* base = nnet + (size_t)b * T_DIM * C_DIM;
    const int* ysb = ys + b * U_DIM;
    const float* Ab = A + (size_t)b * T_DIM * U_DIM;
    const int lab1 = ysb[min(u1, U_DIM - 1)];
    const int lab3 = ysb[min(u3, U_DIM - 1)];
    const int labn = ysb[min(u3 + 1, U_DIM - 1)];
    const bool skipA = (s1 < 199) && (lab3 != lab1);
    const bool skipB = (s3 < 199) && (labn != lab3);
    const int ty = 2 * yl;
    const bool v0 = (s0 <= 200) && (s0 <= ty);
    const bool v1 = (s1 <= 200) && (s1 <= ty);
    const bool v2 = (s2 <= 200) && (s2 <= ty);
    const bool v3 = (s3 <= 200) && (s3 <= ty);
    const bool st = (L < 50);
    const float f0 = (s0 == ty || s0 == ty - 1) ? 0.0f : NEGINF;
    const float f1 = (s1 == ty || s1 == ty - 1) ? 0.0f : NEGINF;
    const float f2 = (s2 == ty || s2 == ty - 1) ? 0.0f : NEGINF;
    const float f3 = (s3 == ty || s3 == ty - 1) ? 0.0f : NEGINF;
    const float inv_hl = 1.0f / (float)hl;

    float b0 = NEGINF, b1 = NEGINF, b2 = NEGINF, b3 = NEGINF;
    float prev1 = NEGINF, prev3 = NEGINF;
    float m1 = NEGINF, ss1 = 0.0f, m3 = NEGINF, ss3 = 0.0f;

    float rb[4], r1[4], r3[4], ra1[4], ra3[4];
    rb[0] = NEGINF; r1[0] = NEGINF; r3[0] = NEGINF;
#pragma unroll
    for (int k = 1; k < 4; ++k) {
        const float* r = base + (size_t)(T_DIM - k) * C_DIM;
        rb[k] = r[0]; r1[k] = r[lab1]; r3[k] = r[lab3];
    }
#pragma unroll
    for (int k = 0; k < 4; ++k) {
        if (st) {
            ra1[k] = Ab[(size_t)(T_DIM - 1 - k) * U_DIM + u1];
            ra3[k] = Ab[(size_t)(T_DIM - 1 - k) * U_DIM + u3];
        } else { ra1[k] = NEGINF; ra3[k] = NEGINF; }
    }
    for (int ob = 0; ob < T_DIM; ob += 4) {
#pragma unroll
        for (int k = 0; k < 4; ++k) {
            const int t = T_DIM - 1 - ob - k;
            float ph0 = v0 ? rb[k] : NEGINF;
            float ph1 = v1 ? r1[k] : NEGINF;
            float ph2 = v2 ? rb[k] : NEGINF;
            float ph3 = v3 ? r3[k] : NEGINF;
            float a1v = ra1[k], a3v = ra3[k];
            if (t - 3 >= 1) {
                const float* r = base + (size_t)(t - 3) * C_DIM;
                rb[k] = r[0]; r1[k] = r[lab1]; r3[k] = r[lab3];
            }
            if (t - 4 >= 0 && st) {
                ra1[k] = Ab[(size_t)(t - 4) * U_DIM + u1];
                ra3[k] = Ab[(size_t)(t - 4) * U_DIM + u3];
            }
            float q0 = ph0 + b0, q1 = ph1 + b1, q2 = ph2 + b2, q3 = ph3 + b3;
            float qd0 = __shfl_down(q0, 1, 64);
            float qd1 = __shfl_down(q1, 1, 64);
            if (L == 63) { qd0 = NEGINF; qd1 = NEGINF; }
            float n0 = lse2f(q0, q1);
            float n1 = lse3f(q1, q2, skipA ? q3 : NEGINF);
            float n2 = lse2f(q2, q3);
            float n3 = lse3f(q3, qd0, skipB ? qd1 : NEGINF);
            bool fin = (t == hl - 1);
            b0 = fin ? f0 : n0;
            b1 = fin ? f1 : n1;
            b2 = fin ? f2 : n2;
            b3 = fin ? f3 : n3;
            if (st) {
                float risk = 0.1f * (float)t * inv_hl;
                float bl1 = (a1v == NEGINF) ? NEGINF : b1;
                float bp1 = log_sub_expf(bl1, prev1 + ph1);
                float x1 = a1v + bp1 - risk;
                if (x1 != NEGINF) {
                    float nm = fmaxf(m1, x1);
                    ss1 = ss1 * __expf(m1 - nm) + __expf(x1 - nm);
                    m1 = nm;
                }
                prev1 = bl1;
                float bl3 = (a3v == NEGINF) ? NEGINF : b3;
                float bp3 = log_sub_expf(bl3, prev3 + ph3);
                float x3 = a3v + bp3 - risk;
                if (x3 != NEGINF) {
                    float nm = fmaxf(m3, x3);
                    ss3 = ss3 * __expf(m3 - nm) + __expf(x3 - nm);
                    m3 = nm;
                }
                prev3 = bl3;
            }
        }
    }
    __shared__ float shlu[U_DIM];
    if (st) {
        shlu[u1] = (m1 == NEGINF) ? NEGINF : (m1 + __logf(ss1));
        shlu[u3] = (m3 == NEGINF) ? NEGINF : (m3 + __logf(ss3));
    }
    __syncthreads();
    if (threadIdx.x == 0) {
        int cnt = 0;
        for (int u = 0; u < U_DIM; ++u) cnt += (shlu[u] != NEGINF) ? 1 : 0;
        int last = cnt - 1;
        last = last < 0 ? 0 : (last > U_DIM - 1 ? U_DIM - 1 : last);
        out[b] = -shlu[last];
    }
}

extern "C" void kernel_launch(void* const* d_in, const int* in_sizes, int n_in,
                              void* d_out, int out_size, void* d_ws, size_t ws_size,
                              hipStream_t stream) {
    const float* nnet  = (const float*)d_in[0];
    const int*   ys    = (const int*)d_in[1];
    const int*   hlens = (const int*)d_in[2];
    const int*   ylens = (const int*)d_in[3];
    float*       outp  = (float*)d_out;
    const int B = in_sizes[2];
    const size_t TP = T_DIM + 2 * PAD;
    const size_t szP  = (size_t)B * TP * U_DIM;
    const size_t szPB = (size_t)B * TP;
    const size_t szA  = (size_t)B * AROWS * U_DIM;
    const size_t need = (szP + szPB + 2 * szA) * sizeof(float);

    if (ws_size >= need) {
        float* P    = (float*)d_ws;
        float* PB   = P + szP;
        float* A    = PB + szPB;
        float* Braw = A + szA;
        brctc_mega<<<B, 1024, 0, stream>>>(nnet, ys, hlens, ylens,
                                           P, PB, A, Braw, outp);
    } else {
        float* A = (float*)d_ws;
        brctc_fwd64<<<B, 64, 0, stream>>>(nnet, ys, hlens, ylens, A);
        brctc_bwd64<<<B, 64, 0, stream>>>(nnet, ys, hlens, ylens, A, outp);
    }
}

// Round 7
// 542.291 us; speedup vs baseline: 1.2943x; 1.1308x over previous
//
#include <hip/hip_runtime.h>
#include <math.h>

#define T_DIM 1000
#define C_DIM 500
#define U_DIM 100
#define PAD   16          // head/tail padding rows for P/PB (ring over-reads)
#define AROWS (T_DIM + 5) // A/Braw rows (loss ring reads to row T+4)
#define NEGINF (-INFINITY)

__device__ __forceinline__ float lse2f(float a, float b) {
    float m = fmaxf(a, b);
    if (m == NEGINF) return NEGINF;
    float mn = fminf(a, b);
    return m + __logf(1.0f + __expf(mn - m));
}

__device__ __forceinline__ float lse3f(float x1, float x2, float x3) {
    float m = fmaxf(fmaxf(x1, x2), x3);
    if (m == NEGINF) return NEGINF;
    return m + __logf(__expf(x1 - m) + __expf(x2 - m) + __expf(x3 - m));
}

// Bug-compatible replica of reference _log_sub_exp (incl. inf-substitution quirk).
__device__ __forceinline__ float log_sub_expf(float a, float b) {
    bool ia = isinf(a), ib = isinf(b);
    if (!ia && !ib) {
        float ans = b + __logf(__expf(a - b) - 1.0f);
        if (isinf(ans)) ans = -2001.0f + __logf(__expf(1.0f) - 1.0f);
        return ans;
    }
    if (!ia && ib) return a;
    return NEGINF;
}

// DPP lane shifts (validated bit-exact in round 6; VALU-only, replaces ds_bpermute)
__device__ __forceinline__ float dpp_shr1(float x) {  // lane L <- L-1; lane0 <- -inf
    int r = __builtin_amdgcn_update_dpp(__float_as_int(NEGINF), __float_as_int(x),
                                        0x138, 0xF, 0xF, false);  // wave_shr:1
    return __int_as_float(r);
}
__device__ __forceinline__ float dpp_shl1(float x) {  // lane L <- L+1; lane63 <- -inf
    int r = __builtin_amdgcn_update_dpp(__float_as_int(NEGINF), __float_as_int(x),
                                        0x130, 0xF, 0xF, false);  // wave_shl:1
    return __int_as_float(r);
}

// ---------- pre-gather: compact label/blank log-probs, fully parallel -------
extern "C" __global__ void __launch_bounds__(256)
brctc_gather(const float* __restrict__ nnet, const int* __restrict__ ys,
             float* __restrict__ P, float* __restrict__ PB)
{
    const int t = blockIdx.x * 2 + (threadIdx.x >> 7);
    const int b = blockIdx.y;
    const int l = threadIdx.x & 127;
    const float* row = nnet + ((size_t)b * T_DIM + t) * C_DIM;
    const size_t TP = T_DIM + 2 * PAD;
    if (l < U_DIM) {
        int lab = ys[b * U_DIM + l];
        P[((size_t)b * TP + PAD + t) * U_DIM + l] = row[lab];
    } else if (l == U_DIM) {
        PB[(size_t)b * TP + PAD + t] = row[0];
    }
}

// ---- forward scan: named-scalar 8-deep ring (registers!), DPP, static loop -
#define FWD_STEP(tt, RL, RPB)                                                \
    {                                                                        \
        float2 pl = RL; float pbv = RPB;                                     \
        RL  = ((const float2*)(Pb + (long)((tt) + 8) * U_DIM))[L];           \
        RPB = PBb[(tt) + 8];                                                 \
        float p0 = v0 ? pbv  : NEGINF;                                       \
        float p1 = v1 ? pl.x : NEGINF;                                       \
        float p2 = v2 ? pbv  : NEGINF;                                       \
        float p3 = v3 ? pl.y : NEGINF;                                       \
        float am1 = dpp_shr1(a3);                                            \
        float n0 = p0 + lse2f(a0, am1);                                      \
        float n1 = p1 + lse3f(a1, a0, skip1 ? am1 : NEGINF);                 \
        float n2 = p2 + lse2f(a2, a1);                                       \
        float n3 = p3 + lse3f(a3, a2, skip3 ? a1 : NEGINF);                  \
        a0 = n0; a1 = n1; a2 = n2; a3 = n3;                                  \
        if (st) {                                                            \
            bool live = ((tt) < hl);                                         \
            ((float2*)(Ab + (size_t)(tt) * U_DIM))[L] =                      \
                make_float2(live ? n1 : NEGINF, live ? n3 : NEGINF);         \
        }                                                                    \
    }

__device__ __forceinline__ void fwd_scan4(const float* __restrict__ Pb,
                                          const float* __restrict__ PBb,
                                          const int* __restrict__ ysb,
                                          int hl, int yl,
                                          float* __restrict__ Ab)
{
    const int L = threadIdx.x & 63;
    const int s1 = 4 * L + 1, s3 = 4 * L + 3;
    const int u1 = 2 * L;
    const int lab1 = ysb[min(u1, U_DIM - 1)];
    const int lab3 = ysb[min(u1 + 1, U_DIM - 1)];
    const int labm = ysb[min(max(u1 - 1, 0), U_DIM - 1)];
    const bool skip1 = (s1 >= 3) && (lab1 != labm);
    const bool skip3 = (lab3 != lab1);
    const int ty = 2 * yl;
    const bool v0 = (4 * L     <= 200) && (4 * L     <= ty);
    const bool v1 = (s1        <= 200) && (s1        <= ty);
    const bool v2 = (4 * L + 2 <= 200) && (4 * L + 2 <= ty);
    const bool v3 = (s3        <= 200) && (s3        <= ty);
    const bool st = (L < 50);

    float a0 = (L == 0) ? 0.0f : NEGINF, a1 = NEGINF, a2 = NEGINF, a3 = NEGINF;

    // ring slot j holds p row (tb + j); all refills unconditional into pad
    float2 rA, rB, rC, rD, rE, rF, rG, rH;
    float  gA, gB, gC, gD, gE, gF, gG, gH;
    rA = ((const float2*)(Pb + 0L * U_DIM))[L]; gA = PBb[0];
    rB = ((const float2*)(Pb + 1L * U_DIM))[L]; gB = PBb[1];
    rC = ((const float2*)(Pb + 2L * U_DIM))[L]; gC = PBb[2];
    rD = ((const float2*)(Pb + 3L * U_DIM))[L]; gD = PBb[3];
    rE = ((const float2*)(Pb + 4L * U_DIM))[L]; gE = PBb[4];
    rF = ((const float2*)(Pb + 5L * U_DIM))[L]; gF = PBb[5];
    rG = ((const float2*)(Pb + 6L * U_DIM))[L]; gG = PBb[6];
    rH = ((const float2*)(Pb + 7L * U_DIM))[L]; gH = PBb[7];

    for (int tb = 0; tb < T_DIM; tb += 8) {
        FWD_STEP(tb + 0, rA, gA)
        FWD_STEP(tb + 1, rB, gB)
        FWD_STEP(tb + 2, rC, gC)
        FWD_STEP(tb + 3, rD, gD)
        FWD_STEP(tb + 4, rE, gE)
        FWD_STEP(tb + 5, rF, gF)
        FWD_STEP(tb + 6, rG, gG)
        FWD_STEP(tb + 7, rH, gH)
    }
    // sentinel row T = -inf (a_next at t = T-1 in loss phase)
    if (st) ((float2*)(Ab + (size_t)T_DIM * U_DIM))[L] = make_float2(NEGINF, NEGINF);
}

// ---- backward scan: named-scalar ring, DPP, static loop, per-step fin ------
#define BWD_STEP(tt, RL, RPB)                                                \
    {                                                                        \
        float2 pl = RL; float pbv = RPB;                                     \
        RL  = ((const float2*)(Pb + (long)((tt) - 7) * U_DIM))[L];           \
        RPB = PBb[(tt) - 7];                                                 \
        float ph0 = v0 ? pbv  : NEGINF;                                      \
        float ph1 = v1 ? pl.x : NEGINF;                                      \
        float ph2 = v2 ? pbv  : NEGINF;                                      \
        float ph3 = v3 ? pl.y : NEGINF;                                      \
        float q0 = ph0 + b0, q1 = ph1 + b1, q2 = ph2 + b2, q3 = ph3 + b3;    \
        float qd0 = dpp_shl1(q0);                                            \
        float qd1 = dpp_shl1(q1);                                            \
        float n0 = lse2f(q0, q1);                                            \
        float n1 = lse3f(q1, q2, skipA ? q3 : NEGINF);                       \
        float n2 = lse2f(q2, q3);                                            \
        float n3 = lse3f(q3, qd0, skipB ? qd1 : NEGINF);                     \
        bool fin = ((tt) == hl - 1);                                         \
        b0 = fin ? f0 : n0;                                                  \
        b1 = fin ? f1 : n1;                                                  \
        b2 = fin ? f2 : n2;                                                  \
        b3 = fin ? f3 : n3;                                                  \
        if (st)                                                              \
            ((float2*)(Bb + (size_t)(tt) * U_DIM))[L] = make_float2(b1, b3); \
    }

__device__ __forceinline__ void bwd_scan4(const float* __restrict__ Pb,
                                          const float* __restrict__ PBb,
                                          const int* __restrict__ ysb,
                                          int hl, int yl,
                                          float* __restrict__ Bb)
{
    const int L = threadIdx.x & 63;
    const int s0 = 4 * L, s1 = 4 * L + 1, s2 = 4 * L + 2, s3 = 4 * L + 3;
    const int u1 = 2 * L;
    const int lab1 = ysb[min(u1, U_DIM - 1)];
    const int lab3 = ysb[min(u1 + 1, U_DIM - 1)];
    const int labn = ysb[min(u1 + 2, U_DIM - 1)];
    const bool skipA = (s1 < 199) && (lab3 != lab1);
    const bool skipB = (s3 < 199) && (labn != lab3);
    const int ty = 2 * yl;
    const bool v0 = (s0 <= 200) && (s0 <= ty);
    const bool v1 = (s1 <= 200) && (s1 <= ty);
    const bool v2 = (s2 <= 200) && (s2 <= ty);
    const bool v3 = (s3 <= 200) && (s3 <= ty);
    const bool st = (L < 50);
    const float f0 = (s0 == ty || s0 == ty - 1) ? 0.0f : NEGINF;
    const float f1 = (s1 == ty || s1 == ty - 1) ? 0.0f : NEGINF;
    const float f2 = (s2 == ty || s2 == ty - 1) ? 0.0f : NEGINF;
    const float f3 = (s3 == ty || s3 == ty - 1) ? 0.0f : NEGINF;

    float b0 = NEGINF, b1 = NEGINF, b2 = NEGINF, b3 = NEGINF;

    // slot j holds p row (999 - j + 1) = 1000-j initially; row 1000 == -inf
    float2 sA, sB, sC, sD, sE, sF, sG, sH;
    float  hA, hB, hC, hD, hE, hF, hG, hH;
    sA = make_float2(NEGINF, NEGINF); hA = NEGINF;
    sB = ((const float2*)(Pb + 999L * U_DIM))[L]; hB = PBb[999];
    sC = ((const float2*)(Pb + 998L * U_DIM))[L]; hC = PBb[998];
    sD = ((const float2*)(Pb + 997L * U_DIM))[L]; hD = PBb[997];
    sE = ((const float2*)(Pb + 996L * U_DIM))[L]; hE = PBb[996];
    sF = ((const float2*)(Pb + 995L * U_DIM))[L]; hF = PBb[995];
    sG = ((const float2*)(Pb + 994L * U_DIM))[L]; hG = PBb[994];
    sH = ((const float2*)(Pb + 993L * U_DIM))[L]; hH = PBb[993];

    for (int ob = 0; ob < T_DIM; ob += 8) {
        BWD_STEP(999 - ob, sA, hA)
        BWD_STEP(998 - ob, sB, hB)
        BWD_STEP(997 - ob, sC, hC)
        BWD_STEP(996 - ob, sD, hD)
        BWD_STEP(995 - ob, sE, hE)
        BWD_STEP(994 - ob, sF, hF)
        BWD_STEP(993 - ob, sG, hG)
        BWD_STEP(992 - ob, sH, hH)
    }
}

// ---- loss step: named-scalar 4-deep ring, fully static slots ---------------
#define LSTEP(tt, RA, RB, RP)                                                \
    {                                                                        \
        float a_nx = RA, br_nx = RB, p_nx = RP;                              \
        RA = Ab[(long)((tt) + 5) * U_DIM + u];                               \
        RB = Bb[(long)((tt) + 5) * U_DIM + u];                               \
        RP = valu ? Pb[(long)((tt) + 5) * U_DIM + u] : NEGINF;               \
        float bl   = (a_t  == NEGINF) ? NEGINF : braw_t;                     \
        float term = (a_nx == NEGINF) ? NEGINF : (br_nx + p_nx);             \
        float bp = log_sub_expf(bl, term);                                   \
        float x = a_t + bp - 0.1f * (float)(tt) * inv_hl;                    \
        if (x != NEGINF) {                                                   \
            float nm = fmaxf(m, x);                                          \
            ssum = ssum * __expf(m - nm) + __expf(x - nm);                   \
            m = nm;                                                          \
        }                                                                    \
        a_t = a_nx; braw_t = br_nx;                                          \
    }

// ------------------- fused: fwd wave + bwd wave + 8-way loss ----------------
extern "C" __global__ void __launch_bounds__(1024)
brctc_fused(const float* __restrict__ P, const float* __restrict__ PB,
            const int* __restrict__ ys, const int* __restrict__ hlens,
            const int* __restrict__ ylens,
            float* __restrict__ A, float* __restrict__ Braw,
            float* __restrict__ out)
{
    const int b = blockIdx.x;
    const int tid = threadIdx.x;
    const int w = tid >> 6;
    const int hl = hlens[b], yl = ylens[b];
    const size_t TP = T_DIM + 2 * PAD;
    const float* Pb  = P  + ((size_t)b * TP + PAD) * U_DIM;
    const float* PBb = PB + (size_t)b * TP + PAD;
    const int* ysb = ys + b * U_DIM;
    float* Ab = A    + (size_t)b * AROWS * U_DIM;
    float* Bb = Braw + (size_t)b * AROWS * U_DIM;

    if (w == 0)      fwd_scan4(Pb, PBb, ysb, hl, yl, Ab);
    else if (w == 1) bwd_scan4(Pb, PBb, ysb, hl, yl, Bb);
    __syncthreads();

    __shared__ float shm[8][U_DIM], shs[8][U_DIM], shlu[U_DIM];
    {
        const int u = tid & 127;
        const int c = tid >> 7;               // 0..7
        if (u < U_DIM) {
            const bool valu = (u < yl);       // p_l valid mask (s=2u+1 <= 2yl)
            const float inv_hl = 1.0f / (float)hl;
            const int t0 = 125 * c;           // t0 % 4 == 0
            float a_t    = Ab[(size_t)t0 * U_DIM + u];
            float braw_t = Bb[(size_t)t0 * U_DIM + u];
            // slot for row r is (r - t0 - 1) & 3
            float aA = Ab[(long)(t0 + 1) * U_DIM + u];
            float aB = Ab[(long)(t0 + 2) * U_DIM + u];
            float aC = Ab[(long)(t0 + 3) * U_DIM + u];
            float aD = Ab[(long)(t0 + 4) * U_DIM + u];
            float bA = Bb[(long)(t0 + 1) * U_DIM + u];
            float bB = Bb[(long)(t0 + 2) * U_DIM + u];
            float bC = Bb[(long)(t0 + 3) * U_DIM + u];
            float bD = Bb[(long)(t0 + 4) * U_DIM + u];
            float pA = valu ? Pb[(long)(t0 + 1) * U_DIM + u] : NEGINF;
            float pB = valu ? Pb[(long)(t0 + 2) * U_DIM + u] : NEGINF;
            float pC = valu ? Pb[(long)(t0 + 3) * U_DIM + u] : NEGINF;
            float pD = valu ? Pb[(long)(t0 + 4) * U_DIM + u] : NEGINF;
            float m = NEGINF, ssum = 0.0f;
            for (int kb = 0; kb < 124; kb += 4) {
                LSTEP(t0 + kb + 0, aA, bA, pA)
                LSTEP(t0 + kb + 1, aB, bB, pB)
                LSTEP(t0 + kb + 2, aC, bC, pC)
                LSTEP(t0 + kb + 3, aD, bD, pD)
            }
            LSTEP(t0 + 124, aA, bA, pA)       // 125th; slot 124&3 == 0
            shm[c][u] = m; shs[c][u] = ssum;
        }
    }
    __syncthreads();
    if (tid < U_DIM) {
        float M = NEGINF;
#pragma unroll
        for (int c = 0; c < 8; ++c) M = fmaxf(M, shm[c][tid]);
        float lu = NEGINF;
        if (M != NEGINF) {
            float s = 0.0f;
#pragma unroll
            for (int c = 0; c < 8; ++c) {
                float mc = shm[c][tid];
                if (mc != NEGINF) s += shs[c][tid] * __expf(mc - M);
            }
            lu = M + __logf(s);
        }
        shlu[tid] = lu;
    }
    __syncthreads();
    if (tid == 0) {
        int cnt = 0;
        for (int u = 0; u < U_DIM; ++u) cnt += (shlu[u] != NEGINF) ? 1 : 0;
        int last = cnt - 1;
        last = last < 0 ? 0 : (last > U_DIM - 1 ? U_DIM - 1 : last);
        out[b] = -shlu[last];
    }
}

// =================== fallback (small ws): round-1-style direct path =========
extern "C" __global__ void __launch_bounds__(256)
brctc_fwd_fb(const float* __restrict__ nnet, const int* __restrict__ ys,
             const int* __restrict__ hlens, const int* __restrict__ ylens,
             float* __restrict__ a_l)
{
    const int b = blockIdx.x;
    const int s = threadIdx.x;
    __shared__ float sh_a[201];
    __shared__ int   sh_ys[U_DIM];
    if (s < U_DIM) sh_ys[s] = ys[b * U_DIM + s];
    __syncthreads();
    const int hl = hlens[b], yl = ylens[b];
    int lab = 0; bool skip = false;
    if (s < 201) {
        if (s & 1) lab = sh_ys[(s - 1) >> 1];
        if ((s & 1) && s >= 3) skip = (sh_ys[(s - 1) >> 1] != sh_ys[(s - 3) >> 1]);
        sh_a[s] = (s == 0) ? 0.0f : NEGINF;
    }
    const bool valid = (s < 201) && (s <= 2 * yl);
    const bool isodd = (s < 201) && (s & 1);
    const int l = (s - 1) >> 1;
    const float* base = nnet + (size_t)b * T_DIM * C_DIM;
    float* alb = a_l + (size_t)b * T_DIM * U_DIM;
    __syncthreads();
    float p_cur = valid ? base[lab] : NEGINF;
    for (int t = 0; t < T_DIM; ++t) {
        float p_nxt = (valid && (t + 1 < T_DIM)) ? base[(size_t)(t + 1) * C_DIM + lab] : NEGINF;
        float x1 = (s < 201) ? sh_a[s] : NEGINF;
        float x2 = (s >= 1 && s < 201) ? sh_a[s - 1] : NEGINF;
        float x3 = skip ? sh_a[s - 2] : NEGINF;
        float anew = p_cur + lse3f(x1, x2, x3);
        __syncthreads();
        if (s < 201) sh_a[s] = anew;
        if (isodd) alb[t * U_DIM + l] = (t < hl) ? anew : NEGINF;
        __syncthreads();
        p_cur = p_nxt;
    }
}

extern "C" __global__ void __launch_bounds__(256)
brctc_bwd_fb(const float* __restrict__ nnet, const int* __restrict__ ys,
             const int* __restrict__ hlens, const int* __restrict__ ylens,
             const float* __restrict__ a_l, float* __restrict__ out)
{
    const int b = blockIdx.x;
    const int s = threadIdx.x;
    __shared__ float sh_b[201], sh_q[201], sh_lu[U_DIM];
    __shared__ int sh_ys[U_DIM];
    if (s < U_DIM) sh_ys[s] = ys[b * U_DIM + s];
    __syncthreads();
    const int hl = hlens[b], yl = ylens[b];
    int lab = 0; bool skip2 = false;
    if (s < 201) {
        if (s & 1) lab = sh_ys[(s - 1) >> 1];
        int s2 = s + 2;
        if (s2 < 201 && (s2 & 1) && s2 >= 3)
            skip2 = (sh_ys[(s2 - 1) >> 1] != sh_ys[(s2 - 3) >> 1]);
        sh_b[s] = NEGINF;
    }
    const bool valid = (s < 201) && (s <= 2 * yl);
    const bool isodd = (s < 201) && (s & 1);
    const int l = (s - 1) >> 1;
    const float fin0 = (s == 2 * yl || s == 2 * yl - 1) ? 0.0f : NEGINF;
    const float* base = nnet + (size_t)b * T_DIM * C_DIM;
    const float* alb = a_l + (size_t)b * T_DIM * U_DIM;
    float m_run = NEGINF, acc = 0.0f, prev_bl = NEGINF, p_hi = NEGINF;
    __syncthreads();
    for (int t = T_DIM - 1; t >= 0; --t) {
        float p_lo = valid ? base[(size_t)t * C_DIM + lab] : NEGINF;
        float a_cur = isodd ? alb[t * U_DIM + l] : NEGINF;
        float q = (s < 201) ? (p_hi + sh_b[s]) : NEGINF;
        if (s < 201) sh_q[s] = q;
        __syncthreads();
        float q2 = (s + 1 < 201) ? sh_q[s + 1] : NEGINF;
        float q3 = skip2 ? sh_q[s + 2] : NEGINF;
        float cand = lse3f(q, q2, q3);
        float bnew = (t == hl - 1) ? fin0 : cand;
        if (s < 201) sh_b[s] = bnew;
        if (isodd) {
            float bl_t = (a_cur == NEGINF) ? NEGINF : bnew;
            float bp = (t == T_DIM - 1) ? bl_t : log_sub_expf(bl_t, prev_bl + p_hi);
            float x = a_cur + bp - 0.1f * ((float)t / (float)hl);
            if (x != NEGINF) {
                if (x <= m_run) acc += __expf(x - m_run);
                else { acc = acc * __expf(m_run - x) + 1.0f; m_run = x; }
            }
            prev_bl = bl_t;
        }
        __syncthreads();
        p_hi = p_lo;
    }
    if (isodd) sh_lu[l] = (m_run == NEGINF) ? NEGINF : (m_run + __logf(acc));
    __syncthreads();
    if (s == 0) {
        int cnt = 0;
        for (int u = 0; u < U_DIM; ++u) cnt += (sh_lu[u] != NEGINF) ? 1 : 0;
        int last = cnt - 1;
        last = last < 0 ? 0 : (last > U_DIM - 1 ? U_DIM - 1 : last);
        out[b] = -sh_lu[last];
    }
}

extern "C" void kernel_launch(void* const* d_in, const int* in_sizes, int n_in,
                              void* d_out, int out_size, void* d_ws, size_t ws_size,
                              hipStream_t stream) {
    const float* nnet  = (const float*)d_in[0];
    const int*   ys    = (const int*)d_in[1];
    const int*   hlens = (const int*)d_in[2];
    const int*   ylens = (const int*)d_in[3];
    float*       outp  = (float*)d_out;
    const int B = in_sizes[2];
    const size_t TP = T_DIM + 2 * PAD;
    const size_t szP  = (size_t)B * TP * U_DIM;
    const size_t szPB = (size_t)B * TP;
    const size_t szA  = (size_t)B * AROWS * U_DIM;
    const size_t need = (szP + szPB + 2 * szA) * sizeof(float);

    if (ws_size >= need) {
        float* P    = (float*)d_ws;
        float* PB   = P + szP;
        float* A    = PB + szPB;
        float* Braw = A + szA;
        brctc_gather<<<dim3(T_DIM / 2, B), 256, 0, stream>>>(nnet, ys, P, PB);
        brctc_fused<<<B, 1024, 0, stream>>>(P, PB, ys, hlens, ylens, A, Braw, outp);
    } else {
        float* A = (float*)d_ws;
        brctc_fwd_fb<<<B, 256, 0, stream>>>(nnet, ys, hlens, ylens, A);
        brctc_bwd_fb<<<B, 256, 0, stream>>>(nnet, ys, hlens, ylens, A, outp);
    }
}

// Round 8
// 522.577 us; speedup vs baseline: 1.3432x; 1.0377x over previous
//
#include <hip/hip_runtime.h>
#include <math.h>

#define T_DIM 1000
#define C_DIM 500
#define U_DIM 100
#define PAD   16          // head/tail padding rows for P/PB (pipeline over-reads)
#define AROWS (T_DIM + 5) // A/Braw rows (loss pipeline reads to row T+4)
#define NEGINF (-INFINITY)

__device__ __forceinline__ float lse2f(float a, float b) {
    float m = fmaxf(a, b);
    if (m == NEGINF) return NEGINF;
    float mn = fminf(a, b);
    return m + __logf(1.0f + __expf(mn - m));
}

__device__ __forceinline__ float lse3f(float x1, float x2, float x3) {
    float m = fmaxf(fmaxf(x1, x2), x3);
    if (m == NEGINF) return NEGINF;
    return m + __logf(__expf(x1 - m) + __expf(x2 - m) + __expf(x3 - m));
}

// Bug-compatible replica of reference _log_sub_exp (incl. inf-substitution quirk).
__device__ __forceinline__ float log_sub_expf(float a, float b) {
    bool ia = isinf(a), ib = isinf(b);
    if (!ia && !ib) {
        float ans = b + __logf(__expf(a - b) - 1.0f);
        if (isinf(ans)) ans = -2001.0f + __logf(__expf(1.0f) - 1.0f);
        return ans;
    }
    if (!ia && ib) return a;
    return NEGINF;
}

// DPP lane shifts (validated bit-exact rounds 6/7)
__device__ __forceinline__ float dpp_shr1(float x) {  // lane L <- L-1; lane0 <- -inf
    int r = __builtin_amdgcn_update_dpp(__float_as_int(NEGINF), __float_as_int(x),
                                        0x138, 0xF, 0xF, false);  // wave_shr:1
    return __int_as_float(r);
}
__device__ __forceinline__ float dpp_shl1(float x) {  // lane L <- L+1; lane63 <- -inf
    int r = __builtin_amdgcn_update_dpp(__float_as_int(NEGINF), __float_as_int(x),
                                        0x130, 0xF, 0xF, false);  // wave_shl:1
    return __int_as_float(r);
}

#define SCHED_FENCE() __builtin_amdgcn_sched_barrier(0)

// ---------- pre-gather: 5 rows/thread (5 loads in flight), fully parallel ---
extern "C" __global__ void __launch_bounds__(256)
brctc_gather(const float* __restrict__ nnet, const int* __restrict__ ys,
             float* __restrict__ P, float* __restrict__ PB)
{
    const int b = blockIdx.y;
    const int g = blockIdx.x * 2 + (threadIdx.x >> 7);   // 0..199
    const int l = threadIdx.x & 127;
    const int t0 = g * 5;
    const size_t TP = T_DIM + 2 * PAD;
    const float* rowb = nnet + ((size_t)b * T_DIM + t0) * C_DIM;
    if (l < U_DIM) {
        int lab = ys[b * U_DIM + l];
        float* Pr = P + ((size_t)b * TP + PAD + t0) * U_DIM;
#pragma unroll
        for (int i = 0; i < 5; ++i)
            Pr[(size_t)i * U_DIM + l] = rowb[(size_t)i * C_DIM + lab];
    } else if (l == U_DIM) {
        float* PBr = PB + (size_t)b * TP + PAD + t0;
#pragma unroll
        for (int i = 0; i < 5; ++i)
            PBr[i] = rowb[(size_t)i * C_DIM];
    }
}

#define LD2(r) (((const float2*)(Pb + (long)(r) * U_DIM))[L])

// ---------------- forward scan: double-buffered 8-blocks, sched-fenced ------
#define FWD_STEP(tt, PL, PBV)                                                \
    {                                                                        \
        float p0 = v0 ? (PBV)  : NEGINF;                                     \
        float p1 = v1 ? (PL).x : NEGINF;                                     \
        float p2 = v2 ? (PBV)  : NEGINF;                                     \
        float p3 = v3 ? (PL).y : NEGINF;                                     \
        float am1 = dpp_shr1(a3);                                            \
        float n0 = p0 + lse2f(a0, am1);                                      \
        float n1 = p1 + lse3f(a1, a0, skip1 ? am1 : NEGINF);                 \
        float n2 = p2 + lse2f(a2, a1);                                       \
        float n3 = p3 + lse3f(a3, a2, skip3 ? a1 : NEGINF);                  \
        a0 = n0; a1 = n1; a2 = n2; a3 = n3;                                  \
        if (st) {                                                            \
            bool live = ((tt) < hl);                                         \
            ((float2*)(Ab + (size_t)(tt) * U_DIM))[L] =                      \
                make_float2(live ? n1 : NEGINF, live ? n3 : NEGINF);         \
        }                                                                    \
    }

__device__ __forceinline__ void fwd_scan5(const float* __restrict__ Pb,
                                          const float* __restrict__ PBb,
                                          const int* __restrict__ ysb,
                                          int hl, int yl,
                                          float* __restrict__ Ab)
{
    const int L = threadIdx.x & 63;
    const int s1 = 4 * L + 1, s3 = 4 * L + 3;
    const int u1 = 2 * L;
    const int lab1 = ysb[min(u1, U_DIM - 1)];
    const int lab3 = ysb[min(u1 + 1, U_DIM - 1)];
    const int labm = ysb[min(max(u1 - 1, 0), U_DIM - 1)];
    const bool skip1 = (s1 >= 3) && (lab1 != labm);
    const bool skip3 = (lab3 != lab1);
    const int ty = 2 * yl;
    const bool v0 = (4 * L     <= 200) && (4 * L     <= ty);
    const bool v1 = (s1        <= 200) && (s1        <= ty);
    const bool v2 = (4 * L + 2 <= 200) && (4 * L + 2 <= ty);
    const bool v3 = (s3        <= 200) && (s3        <= ty);
    const bool st = (L < 50);

    float a0 = (L == 0) ? 0.0f : NEGINF, a1 = NEGINF, a2 = NEGINF, a3 = NEGINF;

    float2 pA0, pA1, pA2, pA3, pA4, pA5, pA6, pA7;
    float2 pB0, pB1, pB2, pB3, pB4, pB5, pB6, pB7;
    float  qA0, qA1, qA2, qA3, qA4, qA5, qA6, qA7;
    float  qB0, qB1, qB2, qB3, qB4, qB5, qB6, qB7;

    pA0 = LD2(0); qA0 = PBb[0];  pA1 = LD2(1); qA1 = PBb[1];
    pA2 = LD2(2); qA2 = PBb[2];  pA3 = LD2(3); qA3 = PBb[3];
    pA4 = LD2(4); qA4 = PBb[4];  pA5 = LD2(5); qA5 = PBb[5];
    pA6 = LD2(6); qA6 = PBb[6];  pA7 = LD2(7); qA7 = PBb[7];

    for (int tb = 0; tb < T_DIM; tb += 8) {
        const int nb = tb + 8;     // last block loads rows 1000..1007 (pad, unused)
        pB0 = LD2(nb + 0); qB0 = PBb[nb + 0];
        pB1 = LD2(nb + 1); qB1 = PBb[nb + 1];
        pB2 = LD2(nb + 2); qB2 = PBb[nb + 2];
        pB3 = LD2(nb + 3); qB3 = PBb[nb + 3];
        pB4 = LD2(nb + 4); qB4 = PBb[nb + 4];
        pB5 = LD2(nb + 5); qB5 = PBb[nb + 5];
        pB6 = LD2(nb + 6); qB6 = PBb[nb + 6];
        pB7 = LD2(nb + 7); qB7 = PBb[nb + 7];
        SCHED_FENCE();
        FWD_STEP(tb + 0, pA0, qA0)
        FWD_STEP(tb + 1, pA1, qA1)
        FWD_STEP(tb + 2, pA2, qA2)
        FWD_STEP(tb + 3, pA3, qA3)
        FWD_STEP(tb + 4, pA4, qA4)
        FWD_STEP(tb + 5, pA5, qA5)
        FWD_STEP(tb + 6, pA6, qA6)
        FWD_STEP(tb + 7, pA7, qA7)
        SCHED_FENCE();
        pA0 = pB0; qA0 = qB0;  pA1 = pB1; qA1 = qB1;
        pA2 = pB2; qA2 = qB2;  pA3 = pB3; qA3 = qB3;
        pA4 = pB4; qA4 = qB4;  pA5 = pB5; qA5 = qB5;
        pA6 = pB6; qA6 = qB6;  pA7 = pB7; qA7 = qB7;
    }
    // sentinel row T = -inf (a_next at t = T-1 in loss phase)
    if (st) ((float2*)(Ab + (size_t)T_DIM * U_DIM))[L] = make_float2(NEGINF, NEGINF);
}

// ---------------- backward scan: double-buffered 8-blocks, sched-fenced -----
#define BWD_STEP(tt, PL, PBV)                                                \
    {                                                                        \
        float ph0 = v0 ? (PBV)  : NEGINF;                                    \
        float ph1 = v1 ? (PL).x : NEGINF;                                    \
        float ph2 = v2 ? (PBV)  : NEGINF;                                    \
        float ph3 = v3 ? (PL).y : NEGINF;                                    \
        float q0 = ph0 + b0, q1 = ph1 + b1, q2 = ph2 + b2, q3 = ph3 + b3;    \
        float qd0 = dpp_shl1(q0);                                            \
        float qd1 = dpp_shl1(q1);                                            \
        float n0 = lse2f(q0, q1);                                            \
        float n1 = lse3f(q1, q2, skipA ? q3 : NEGINF);                       \
        float n2 = lse2f(q2, q3);                                            \
        float n3 = lse3f(q3, qd0, skipB ? qd1 : NEGINF);                     \
        bool fin = ((tt) == hl - 1);                                         \
        b0 = fin ? f0 : n0;                                                  \
        b1 = fin ? f1 : n1;                                                  \
        b2 = fin ? f2 : n2;                                                  \
        b3 = fin ? f3 : n3;                                                  \
        if (st)                                                              \
            ((float2*)(Bb + (size_t)(tt) * U_DIM))[L] = make_float2(b1, b3); \
    }

__device__ __forceinline__ void bwd_scan5(const float* __restrict__ Pb,
                                          const float* __restrict__ PBb,
                                          const int* __restrict__ ysb,
                                          int hl, int yl,
                                          float* __restrict__ Bb)
{
    const int L = threadIdx.x & 63;
    const int s0 = 4 * L, s1 = 4 * L + 1, s2 = 4 * L + 2, s3 = 4 * L + 3;
    const int u1 = 2 * L;
    const int lab1 = ysb[min(u1, U_DIM - 1)];
    const int lab3 = ysb[min(u1 + 1, U_DIM - 1)];
    const int labn = ysb[min(u1 + 2, U_DIM - 1)];
    const bool skipA = (s1 < 199) && (lab3 != lab1);
    const bool skipB = (s3 < 199) && (labn != lab3);
    const int ty = 2 * yl;
    const bool v0 = (s0 <= 200) && (s0 <= ty);
    const bool v1 = (s1 <= 200) && (s1 <= ty);
    const bool v2 = (s2 <= 200) && (s2 <= ty);
    const bool v3 = (s3 <= 200) && (s3 <= ty);
    const bool st = (L < 50);
    const float f0 = (s0 == ty || s0 == ty - 1) ? 0.0f : NEGINF;
    const float f1 = (s1 == ty || s1 == ty - 1) ? 0.0f : NEGINF;
    const float f2 = (s2 == ty || s2 == ty - 1) ? 0.0f : NEGINF;
    const float f3 = (s3 == ty || s3 == ty - 1) ? 0.0f : NEGINF;

    float b0 = NEGINF, b1 = NEGINF, b2 = NEGINF, b3 = NEGINF;

    // buffer A holds q-rows (t+1) for the current t-block, descending:
    // slot j <=> row (base - j + 1). Row 1000 is pad garbage: harmless,
    // it is only ever added to the initial -inf carry (q = ph + (-inf)).
    float2 pA0, pA1, pA2, pA3, pA4, pA5, pA6, pA7;
    float2 pB0, pB1, pB2, pB3, pB4, pB5, pB6, pB7;
    float  qA0, qA1, qA2, qA3, qA4, qA5, qA6, qA7;
    float  qB0, qB1, qB2, qB3, qB4, qB5, qB6, qB7;

    pA0 = LD2(1000); qA0 = PBb[1000];   // pad row, never contributes
    pA1 = LD2(999);  qA1 = PBb[999];
    pA2 = LD2(998);  qA2 = PBb[998];
    pA3 = LD2(997);  qA3 = PBb[997];
    pA4 = LD2(996);  qA4 = PBb[996];
    pA5 = LD2(995);  qA5 = PBb[995];
    pA6 = LD2(994);  qA6 = PBb[994];
    pA7 = LD2(993);  qA7 = PBb[993];

    for (int base = 999; base >= 7; base -= 8) {
        const int nb = base - 7;   // next block loads rows nb-0-... = base-7..base-14
        pB0 = LD2(nb - 0); qB0 = PBb[nb - 0];
        pB1 = LD2(nb - 1); qB1 = PBb[nb - 1];
        pB2 = LD2(nb - 2); qB2 = PBb[nb - 2];
        pB3 = LD2(nb - 3); qB3 = PBb[nb - 3];
        pB4 = LD2(nb - 4); qB4 = PBb[nb - 4];
        pB5 = LD2(nb - 5); qB5 = PBb[nb - 5];
        pB6 = LD2(nb - 6); qB6 = PBb[nb - 6];
        pB7 = LD2(nb - 7); qB7 = PBb[nb - 7];   // at base=7: rows 0..-7 (head pad)
        SCHED_FENCE();
        BWD_STEP(base - 0, pA0, qA0)
        BWD_STEP(base - 1, pA1, qA1)
        BWD_STEP(base - 2, pA2, qA2)
        BWD_STEP(base - 3, pA3, qA3)
        BWD_STEP(base - 4, pA4, qA4)
        BWD_STEP(base - 5, pA5, qA5)
        BWD_STEP(base - 6, pA6, qA6)
        BWD_STEP(base - 7, pA7, qA7)
        SCHED_FENCE();
        pA0 = pB0; qA0 = qB0;  pA1 = pB1; qA1 = qB1;
        pA2 = pB2; qA2 = qB2;  pA3 = pB3; qA3 = qB3;
        pA4 = pB4; qA4 = qB4;  pA5 = pB5; qA5 = qB5;
        pA6 = pB6; qA6 = qB6;  pA7 = pB7; qA7 = qB7;
    }
}

// ---- loss step: consume named regs (no refill inside) ----------------------
#define LSTEP(tt, RA, RB, RP)                                                \
    {                                                                        \
        float a_nx = (RA), br_nx = (RB), p_nx = (RP);                        \
        float bl   = (a_t  == NEGINF) ? NEGINF : braw_t;                     \
        float term = (a_nx == NEGINF) ? NEGINF : (br_nx + p_nx);             \
        float bp = log_sub_expf(bl, term);                                   \
        float x = a_t + bp - 0.1f * (float)(tt) * inv_hl;                    \
        if (x != NEGINF) {                                                   \
            float nm = fmaxf(m, x);                                          \
            ssum = ssum * __expf(m - nm) + __expf(x - nm);                   \
            m = nm;                                                          \
        }                                                                    \
        a_t = a_nx; braw_t = br_nx;                                          \
    }

// ------------------- fused: fwd wave + bwd wave + 8-way loss ----------------
extern "C" __global__ void __launch_bounds__(1024)
brctc_fused(const float* __restrict__ P, const float* __restrict__ PB,
            const int* __restrict__ ys, const int* __restrict__ hlens,
            const int* __restrict__ ylens,
            float* __restrict__ A, float* __restrict__ Braw,
            float* __restrict__ out)
{
    const int b = blockIdx.x;
    const int tid = threadIdx.x;
    const int w = tid >> 6;
    const int hl = hlens[b], yl = ylens[b];
    const size_t TP = T_DIM + 2 * PAD;
    const float* Pb  = P  + ((size_t)b * TP + PAD) * U_DIM;
    const float* PBb = PB + (size_t)b * TP + PAD;
    const int* ysb = ys + b * U_DIM;
    float* Ab = A    + (size_t)b * AROWS * U_DIM;
    float* Bb = Braw + (size_t)b * AROWS * U_DIM;

    if (w == 0)      fwd_scan5(Pb, PBb, ysb, hl, yl, Ab);
    else if (w == 1) bwd_scan5(Pb, PBb, ysb, hl, yl, Bb);
    __syncthreads();

    __shared__ float shm[8][U_DIM], shs[8][U_DIM], shlu[U_DIM];
    {
        const int u = tid & 127;
        const int c = tid >> 7;               // 0..7
        if (u < U_DIM) {
            const bool valu = (u < yl);       // p_l valid mask (s=2u+1 <= 2yl)
            const float inv_hl = 1.0f / (float)hl;
            const int t0 = 125 * c;
            float a_t    = Ab[(size_t)t0 * U_DIM + u];
            float braw_t = Bb[(size_t)t0 * U_DIM + u];
            // buffer A = rows t0+kb+1..+4 ; double-buffer with fences
            float aA0 = Ab[(long)(t0 + 1) * U_DIM + u];
            float aA1 = Ab[(long)(t0 + 2) * U_DIM + u];
            float aA2 = Ab[(long)(t0 + 3) * U_DIM + u];
            float aA3 = Ab[(long)(t0 + 4) * U_DIM + u];
            float bA0 = Bb[(long)(t0 + 1) * U_DIM + u];
            float bA1 = Bb[(long)(t0 + 2) * U_DIM + u];
            float bA2 = Bb[(long)(t0 + 3) * U_DIM + u];
            float bA3 = Bb[(long)(t0 + 4) * U_DIM + u];
            float pA0 = valu ? Pb[(long)(t0 + 1) * U_DIM + u] : NEGINF;
            float pA1 = valu ? Pb[(long)(t0 + 2) * U_DIM + u] : NEGINF;
            float pA2 = valu ? Pb[(long)(t0 + 3) * U_DIM + u] : NEGINF;
            float pA3 = valu ? Pb[(long)(t0 + 4) * U_DIM + u] : NEGINF;
            float m = NEGINF, ssum = 0.0f;
            for (int kb = 0; kb <= 120; kb += 4) {     // 31 blocks: t0..t0+123
                long nr = (long)(t0 + kb + 5);
                float aB0 = Ab[(nr + 0) * U_DIM + u];
                float aB1 = Ab[(nr + 1) * U_DIM + u];
                float aB2 = Ab[(nr + 2) * U_DIM + u];
                float aB3 = Ab[(nr + 3) * U_DIM + u];
                float bB0 = Bb[(nr + 0) * U_DIM + u];
                float bB1 = Bb[(nr + 1) * U_DIM + u];
                float bB2 = Bb[(nr + 2) * U_DIM + u];
                float bB3 = Bb[(nr + 3) * U_DIM + u];
                float pB0 = valu ? Pb[(nr + 0) * U_DIM + u] : NEGINF;
                float pB1 = valu ? Pb[(nr + 1) * U_DIM + u] : NEGINF;
                float pB2 = valu ? Pb[(nr + 2) * U_DIM + u] : NEGINF;
                float pB3 = valu ? Pb[(nr + 3) * U_DIM + u] : NEGINF;
                SCHED_FENCE();
                LSTEP(t0 + kb + 0, aA0, bA0, pA0)
                LSTEP(t0 + kb + 1, aA1, bA1, pA1)
                LSTEP(t0 + kb + 2, aA2, bA2, pA2)
                LSTEP(t0 + kb + 3, aA3, bA3, pA3)
                SCHED_FENCE();
                aA0 = aB0; aA1 = aB1; aA2 = aB2; aA3 = aB3;
                bA0 = bB0; bA1 = bB1; bA2 = bB2; bA3 = bB3;
                pA0 = pB0; pA1 = pB1; pA2 = pB2; pA3 = pB3;
            }
            LSTEP(t0 + 124, aA0, bA0, pA0)             // 125th step
            shm[c][u] = m; shs[c][u] = ssum;
        }
    }
    __syncthreads();
    if (tid < U_DIM) {
        float M = NEGINF;
#pragma unroll
        for (int c = 0; c < 8; ++c) M = fmaxf(M, shm[c][tid]);
        float lu = NEGINF;
        if (M != NEGINF) {
            float s = 0.0f;
#pragma unroll
            for (int c = 0; c < 8; ++c) {
                float mc = shm[c][tid];
                if (mc != NEGINF) s += shs[c][tid] * __expf(mc - M);
            }
            lu = M + __logf(s);
        }
        shlu[tid] = lu;
    }
    __syncthreads();
    if (tid == 0) {
        int cnt = 0;
        for (int u = 0; u < U_DIM; ++u) cnt += (shlu[u] != NEGINF) ? 1 : 0;
        int last = cnt - 1;
        last = last < 0 ? 0 : (last > U_DIM - 1 ? U_DIM - 1 : last);
        out[b] = -shlu[last];
    }
}

// =================== fallback (small ws): round-1-style direct path =========
extern "C" __global__ void __launch_bounds__(256)
brctc_fwd_fb(const float* __restrict__ nnet, const int* __restrict__ ys,
             const int* __restrict__ hlens, const int* __restrict__ ylens,
             float* __restrict__ a_l)
{
    const int b = blockIdx.x;
    const int s = threadIdx.x;
    __shared__ float sh_a[201];
    __shared__ int   sh_ys[U_DIM];
    if (s < U_DIM) sh_ys[s] = ys[b * U_DIM + s];
    __syncthreads();
    const int hl = hlens[b], yl = ylens[b];
    int lab = 0; bool skip = false;
    if (s < 201) {
        if (s & 1) lab = sh_ys[(s - 1) >> 1];
        if ((s & 1) && s >= 3) skip = (sh_ys[(s - 1) >> 1] != sh_ys[(s - 3) >> 1]);
        sh_a[s] = (s == 0) ? 0.0f : NEGINF;
    }
    const bool valid = (s < 201) && (s <= 2 * yl);
    const bool isodd = (s < 201) && (s & 1);
    const int l = (s - 1) >> 1;
    const float* base = nnet + (size_t)b * T_DIM * C_DIM;
    float* alb = a_l + (size_t)b * T_DIM * U_DIM;
    __syncthreads();
    float p_cur = valid ? base[lab] : NEGINF;
    for (int t = 0; t < T_DIM; ++t) {
        float p_nxt = (valid && (t + 1 < T_DIM)) ? base[(size_t)(t + 1) * C_DIM + lab] : NEGINF;
        float x1 = (s < 201) ? sh_a[s] : NEGINF;
        float x2 = (s >= 1 && s < 201) ? sh_a[s - 1] : NEGINF;
        float x3 = skip ? sh_a[s - 2] : NEGINF;
        float anew = p_cur + lse3f(x1, x2, x3);
        __syncthreads();
        if (s < 201) sh_a[s] = anew;
        if (isodd) alb[t * U_DIM + l] = (t < hl) ? anew : NEGINF;
        __syncthreads();
        p_cur = p_nxt;
    }
}

extern "C" __global__ void __launch_bounds__(256)
brctc_bwd_fb(const float* __restrict__ nnet, const int* __restrict__ ys,
             const int* __restrict__ hlens, const int* __restrict__ ylens,
             const float* __restrict__ a_l, float* __restrict__ out)
{
    const int b = blockIdx.x;
    const int s = threadIdx.x;
    __shared__ float sh_b[201], sh_q[201], sh_lu[U_DIM];
    __shared__ int sh_ys[U_DIM];
    if (s < U_DIM) sh_ys[s] = ys[b * U_DIM + s];
    __syncthreads();
    const int hl = hlens[b], yl = ylens[b];
    int lab = 0; bool skip2 = false;
    if (s < 201) {
        if (s & 1) lab = sh_ys[(s - 1) >> 1];
        int s2 = s + 2;
        if (s2 < 201 && (s2 & 1) && s2 >= 3)
            skip2 = (sh_ys[(s2 - 1) >> 1] != sh_ys[(s2 - 3) >> 1]);
        sh_b[s] = NEGINF;
    }
    const bool valid = (s < 201) && (s <= 2 * yl);
    const bool isodd = (s < 201) && (s & 1);
    const int l = (s - 1) >> 1;
    const float fin0 = (s == 2 * yl || s == 2 * yl - 1) ? 0.0f : NEGINF;
    const float* base = nnet + (size_t)b * T_DIM * C_DIM;
    const float* alb = a_l + (size_t)b * T_DIM * U_DIM;
    float m_run = NEGINF, acc = 0.0f, prev_bl = NEGINF, p_hi = NEGINF;
    __syncthreads();
    for (int t = T_DIM - 1; t >= 0; --t) {
        float p_lo = valid ? base[(size_t)t * C_DIM + lab] : NEGINF;
        float a_cur = isodd ? alb[t * U_DIM + l] : NEGINF;
        float q = (s < 201) ? (p_hi + sh_b[s]) : NEGINF;
        if (s < 201) sh_q[s] = q;
        __syncthreads();
        float q2 = (s + 1 < 201) ? sh_q[s + 1] : NEGINF;
        float q3 = skip2 ? sh_q[s + 2] : NEGINF;
        float cand = lse3f(q, q2, q3);
        float bnew = (t == hl - 1) ? fin0 : cand;
        if (s < 201) sh_b[s] = bnew;
        if (isodd) {
            float bl_t = (a_cur == NEGINF) ? NEGINF : bnew;
            float bp = (t == T_DIM - 1) ? bl_t : log_sub_expf(bl_t, prev_bl + p_hi);
            float x = a_cur + bp - 0.1f * ((float)t / (float)hl);
            if (x != NEGINF) {
                if (x <= m_run) acc += __expf(x - m_run);
                else { acc = acc * __expf(m_run - x) + 1.0f; m_run = x; }
            }
            prev_bl = bl_t;
        }
        __syncthreads();
        p_hi = p_lo;
    }
    if (isodd) sh_lu[l] = (m_run == NEGINF) ? NEGINF : (m_run + __logf(acc));
    __syncthreads();
    if (s == 0) {
        int cnt = 0;
        for (int u = 0; u < U_DIM; ++u) cnt += (sh_lu[u] != NEGINF) ? 1 : 0;
        int last = cnt - 1;
        last = last < 0 ? 0 : (last > U_DIM - 1 ? U_DIM - 1 : last);
        out[b] = -sh_lu[last];
    }
}

extern "C" void kernel_launch(void* const* d_in, const int* in_sizes, int n_in,
                              void* d_out, int out_size, void* d_ws, size_t ws_size,
                              hipStream_t stream) {
    const float* nnet  = (const float*)d_in[0];
    const int*   ys    = (const int*)d_in[1];
    const int*   hlens = (const int*)d_in[2];
    const int*   ylens = (const int*)d_in[3];
    float*       outp  = (float*)d_out;
    const int B = in_sizes[2];
    const size_t TP = T_DIM + 2 * PAD;
    const size_t szP  = (size_t)B * TP * U_DIM;
    const size_t szPB = (size_t)B * TP;
    const size_t szA  = (size_t)B * AROWS * U_DIM;
    const size_t need = (szP + szPB + 2 * szA) * sizeof(float);

    if (ws_size >= need) {
        float* P    = (float*)d_ws;
        float* PB   = P + szP;
        float* A    = PB + szPB;
        float* Braw = A + szA;
        brctc_gather<<<dim3(T_DIM / 10, B), 256, 0, stream>>>(nnet, ys, P, PB);
        brctc_fused<<<B, 1024, 0, stream>>>(P, PB, ys, hlens, ylens, A, Braw, outp);
    } else {
        float* A = (float*)d_ws;
        brctc_fwd_fb<<<B, 256, 0, stream>>>(nnet, ys, hlens, ylens, A);
        brctc_bwd_fb<<<B, 256, 0, stream>>>(nnet, ys, hlens, ylens, A, outp);
    }
}

// Round 10
// 520.709 us; speedup vs baseline: 1.3480x; 1.0036x over previous
//
#include <hip/hip_runtime.h>
#include <math.h>

#define T_DIM 1000
#define C_DIM 500
#define U_DIM 100
#define PAD   16          // head/tail padding rows for P/PB (pipeline over-reads)
#define AROWS (T_DIM + 5) // A/Braw rows (loss pipeline reads to row T+4)
#define NEGINF (-INFINITY)

__device__ __forceinline__ float lse2f(float a, float b) {
    float m = fmaxf(a, b);
    if (m == NEGINF) return NEGINF;
    float mn = fminf(a, b);
    return m + __logf(1.0f + __expf(mn - m));
}

__device__ __forceinline__ float lse3f(float x1, float x2, float x3) {
    float m = fmaxf(fmaxf(x1, x2), x3);
    if (m == NEGINF) return NEGINF;
    return m + __logf(__expf(x1 - m) + __expf(x2 - m) + __expf(x3 - m));
}

// Bug-compatible replica of reference _log_sub_exp (incl. inf-substitution quirk).
__device__ __forceinline__ float log_sub_expf(float a, float b) {
    bool ia = isinf(a), ib = isinf(b);
    if (!ia && !ib) {
        float ans = b + __logf(__expf(a - b) - 1.0f);
        if (isinf(ans)) ans = -2001.0f + __logf(__expf(1.0f) - 1.0f);
        return ans;
    }
    if (!ia && ib) return a;
    return NEGINF;
}

// DPP lane shifts (validated bit-exact rounds 6/7)
__device__ __forceinline__ float dpp_shr1(float x) {  // lane L <- L-1; lane0 <- -inf
    int r = __builtin_amdgcn_update_dpp(__float_as_int(NEGINF), __float_as_int(x),
                                        0x138, 0xF, 0xF, false);  // wave_shr:1
    return __int_as_float(r);
}
__device__ __forceinline__ float dpp_shl1(float x) {  // lane L <- L+1; lane63 <- -inf
    int r = __builtin_amdgcn_update_dpp(__float_as_int(NEGINF), __float_as_int(x),
                                        0x130, 0xF, 0xF, false);  // wave_shl:1
    return __int_as_float(r);
}

#define SCHED_FENCE() __builtin_amdgcn_sched_barrier(0)
// Register pins: force value to live in a VGPR at this point (defeats load
// sinking / dest-register reuse that collapsed the pipeline in r4-r8).
// NB: macro parameter must NOT be named 'x'/'y' (member-access tokens!).
#define PINF(vv) asm volatile("" : "+v"(vv))
#define PIN2(vv) asm volatile("" : "+v"((vv).x), "+v"((vv).y))

// ---------- pre-gather: 5 rows/thread (5 loads in flight), fully parallel ---
extern "C" __global__ void __launch_bounds__(256)
brctc_gather(const float* __restrict__ nnet, const int* __restrict__ ys,
             float* __restrict__ P, float* __restrict__ PB)
{
    const int b = blockIdx.y;
    const int g = blockIdx.x * 2 + (threadIdx.x >> 7);   // 0..199
    const int l = threadIdx.x & 127;
    const int t0 = g * 5;
    const size_t TP = T_DIM + 2 * PAD;
    const float* rowb = nnet + ((size_t)b * T_DIM + t0) * C_DIM;
    if (l < U_DIM) {
        int lab = ys[b * U_DIM + l];
        float* Pr = P + ((size_t)b * TP + PAD + t0) * U_DIM;
#pragma unroll
        for (int i = 0; i < 5; ++i)
            Pr[(size_t)i * U_DIM + l] = rowb[(size_t)i * C_DIM + lab];
    } else if (l == U_DIM) {
        float* PBr = PB + (size_t)b * TP + PAD + t0;
#pragma unroll
        for (int i = 0; i < 5; ++i)
            PBr[i] = rowb[(size_t)i * C_DIM];
    }
}

#define LD2(r) (((const float2*)(Pb + (long)(r) * U_DIM))[L])

// ---------------- forward scan: double-buffered 8-blocks, pinned regs -------
#define FWD_STEP(tt, PL, PBV)                                                \
    {                                                                        \
        float p0 = v0 ? (PBV)  : NEGINF;                                     \
        float p1 = v1 ? (PL).x : NEGINF;                                     \
        float p2 = v2 ? (PBV)  : NEGINF;                                     \
        float p3 = v3 ? (PL).y : NEGINF;                                     \
        float am1 = dpp_shr1(a3);                                            \
        float n0 = p0 + lse2f(a0, am1);                                      \
        float n1 = p1 + lse3f(a1, a0, skip1 ? am1 : NEGINF);                 \
        float n2 = p2 + lse2f(a2, a1);                                       \
        float n3 = p3 + lse3f(a3, a2, skip3 ? a1 : NEGINF);                  \
        a0 = n0; a1 = n1; a2 = n2; a3 = n3;                                  \
        if (st) {                                                            \
            bool live = ((tt) < hl);                                         \
            ((float2*)(Ab + (size_t)(tt) * U_DIM))[L] =                      \
                make_float2(live ? n1 : NEGINF, live ? n3 : NEGINF);         \
        }                                                                    \
    }

__device__ __forceinline__ void fwd_scan5(const float* __restrict__ Pb,
                                          const float* __restrict__ PBb,
                                          const int* __restrict__ ysb,
                                          int hl, int yl,
                                          float* __restrict__ Ab)
{
    const int L = threadIdx.x & 63;
    const int s1 = 4 * L + 1, s3 = 4 * L + 3;
    const int u1 = 2 * L;
    const int lab1 = ysb[min(u1, U_DIM - 1)];
    const int lab3 = ysb[min(u1 + 1, U_DIM - 1)];
    const int labm = ysb[min(max(u1 - 1, 0), U_DIM - 1)];
    const bool skip1 = (s1 >= 3) && (lab1 != labm);
    const bool skip3 = (lab3 != lab1);
    const int ty = 2 * yl;
    const bool v0 = (4 * L     <= 200) && (4 * L     <= ty);
    const bool v1 = (s1        <= 200) && (s1        <= ty);
    const bool v2 = (4 * L + 2 <= 200) && (4 * L + 2 <= ty);
    const bool v3 = (s3        <= 200) && (s3        <= ty);
    const bool st = (L < 50);

    float a0 = (L == 0) ? 0.0f : NEGINF, a1 = NEGINF, a2 = NEGINF, a3 = NEGINF;

    float2 pA0, pA1, pA2, pA3, pA4, pA5, pA6, pA7;
    float2 pB0, pB1, pB2, pB3, pB4, pB5, pB6, pB7;
    float  qA0, qA1, qA2, qA3, qA4, qA5, qA6, qA7;
    float  qB0, qB1, qB2, qB3, qB4, qB5, qB6, qB7;

    pA0 = LD2(0); qA0 = PBb[0];  pA1 = LD2(1); qA1 = PBb[1];
    pA2 = LD2(2); qA2 = PBb[2];  pA3 = LD2(3); qA3 = PBb[3];
    pA4 = LD2(4); qA4 = PBb[4];  pA5 = LD2(5); qA5 = PBb[5];
    pA6 = LD2(6); qA6 = PBb[6];  pA7 = LD2(7); qA7 = PBb[7];

    for (int tb = 0; tb < T_DIM; tb += 8) {
        const int nb = tb + 8;     // last block loads rows 1000..1007 (pad, unused)
        pB0 = LD2(nb + 0); qB0 = PBb[nb + 0];
        pB1 = LD2(nb + 1); qB1 = PBb[nb + 1];
        pB2 = LD2(nb + 2); qB2 = PBb[nb + 2];
        pB3 = LD2(nb + 3); qB3 = PBb[nb + 3];
        pB4 = LD2(nb + 4); qB4 = PBb[nb + 4];
        pB5 = LD2(nb + 5); qB5 = PBb[nb + 5];
        pB6 = LD2(nb + 6); qB6 = PBb[nb + 6];
        pB7 = LD2(nb + 7); qB7 = PBb[nb + 7];
        SCHED_FENCE();
        FWD_STEP(tb + 0, pA0, qA0)
        FWD_STEP(tb + 1, pA1, qA1)
        FWD_STEP(tb + 2, pA2, qA2)
        FWD_STEP(tb + 3, pA3, qA3)
        FWD_STEP(tb + 4, pA4, qA4)
        FWD_STEP(tb + 5, pA5, qA5)
        FWD_STEP(tb + 6, pA6, qA6)
        FWD_STEP(tb + 7, pA7, qA7)
        SCHED_FENCE();
        // pins: all 24 B values simultaneously live -> distinct VGPR dests
        PIN2(pB0); PIN2(pB1); PIN2(pB2); PIN2(pB3);
        PIN2(pB4); PIN2(pB5); PIN2(pB6); PIN2(pB7);
        PINF(qB0); PINF(qB1); PINF(qB2); PINF(qB3);
        PINF(qB4); PINF(qB5); PINF(qB6); PINF(qB7);
        pA0 = pB0; qA0 = qB0;  pA1 = pB1; qA1 = qB1;
        pA2 = pB2; qA2 = qB2;  pA3 = pB3; qA3 = qB3;
        pA4 = pB4; qA4 = qB4;  pA5 = pB5; qA5 = qB5;
        pA6 = pB6; qA6 = qB6;  pA7 = pB7; qA7 = qB7;
    }
    // sentinel row T = -inf (a_next at t = T-1 in loss phase)
    if (st) ((float2*)(Ab + (size_t)T_DIM * U_DIM))[L] = make_float2(NEGINF, NEGINF);
}

// ---------------- backward scan: double-buffered 8-blocks, pinned regs ------
#define BWD_STEP(tt, PL, PBV)                                                \
    {                                                                        \
        float ph0 = v0 ? (PBV)  : NEGINF;                                    \
        float ph1 = v1 ? (PL).x : NEGINF;                                    \
        float ph2 = v2 ? (PBV)  : NEGINF;                                    \
        float ph3 = v3 ? (PL).y : NEGINF;                                    \
        float q0 = ph0 + b0, q1 = ph1 + b1, q2 = ph2 + b2, q3 = ph3 + b3;    \
        float qd0 = dpp_shl1(q0);                                            \
        float qd1 = dpp_shl1(q1);                                            \
        float n0 = lse2f(q0, q1);                                            \
        float n1 = lse3f(q1, q2, skipA ? q3 : NEGINF);                       \
        float n2 = lse2f(q2, q3);                                            \
        float n3 = lse3f(q3, qd0, skipB ? qd1 : NEGINF);                     \
        bool fin = ((tt) == hl - 1);                                         \
        b0 = fin ? f0 : n0;                                                  \
        b1 = fin ? f1 : n1;                                                  \
        b2 = fin ? f2 : n2;                                                  \
        b3 = fin ? f3 : n3;                                                  \
        if (st)                                                              \
            ((float2*)(Bb + (size_t)(tt) * U_DIM))[L] = make_float2(b1, b3); \
    }

__device__ __forceinline__ void bwd_scan5(const float* __restrict__ Pb,
                                          const float* __restrict__ PBb,
                                          const int* __restrict__ ysb,
                                          int hl, int yl,
                                          float* __restrict__ Bb)
{
    const int L = threadIdx.x & 63;
    const int s0 = 4 * L, s1 = 4 * L + 1, s2 = 4 * L + 2, s3 = 4 * L + 3;
    const int u1 = 2 * L;
    const int lab1 = ysb[min(u1, U_DIM - 1)];
    const int lab3 = ysb[min(u1 + 1, U_DIM - 1)];
    const int labn = ysb[min(u1 + 2, U_DIM - 1)];
    const bool skipA = (s1 < 199) && (lab3 != lab1);
    const bool skipB = (s3 < 199) && (labn != lab3);
    const int ty = 2 * yl;
    const bool v0 = (s0 <= 200) && (s0 <= ty);
    const bool v1 = (s1 <= 200) && (s1 <= ty);
    const bool v2 = (s2 <= 200) && (s2 <= ty);
    const bool v3 = (s3 <= 200) && (s3 <= ty);
    const bool st = (L < 50);
    const float f0 = (s0 == ty || s0 == ty - 1) ? 0.0f : NEGINF;
    const float f1 = (s1 == ty || s1 == ty - 1) ? 0.0f : NEGINF;
    const float f2 = (s2 == ty || s2 == ty - 1) ? 0.0f : NEGINF;
    const float f3 = (s3 == ty || s3 == ty - 1) ? 0.0f : NEGINF;

    float b0 = NEGINF, b1 = NEGINF, b2 = NEGINF, b3 = NEGINF;

    float2 pA0, pA1, pA2, pA3, pA4, pA5, pA6, pA7;
    float2 pB0, pB1, pB2, pB3, pB4, pB5, pB6, pB7;
    float  qA0, qA1, qA2, qA3, qA4, qA5, qA6, qA7;
    float  qB0, qB1, qB2, qB3, qB4, qB5, qB6, qB7;

    pA0 = LD2(1000); qA0 = PBb[1000];   // pad row, never contributes (b=-inf)
    pA1 = LD2(999);  qA1 = PBb[999];
    pA2 = LD2(998);  qA2 = PBb[998];
    pA3 = LD2(997);  qA3 = PBb[997];
    pA4 = LD2(996);  qA4 = PBb[996];
    pA5 = LD2(995);  qA5 = PBb[995];
    pA6 = LD2(994);  qA6 = PBb[994];
    pA7 = LD2(993);  qA7 = PBb[993];

    for (int base = 999; base >= 7; base -= 8) {
        const int nb = base - 7;
        pB0 = LD2(nb - 0); qB0 = PBb[nb - 0];
        pB1 = LD2(nb - 1); qB1 = PBb[nb - 1];
        pB2 = LD2(nb - 2); qB2 = PBb[nb - 2];
        pB3 = LD2(nb - 3); qB3 = PBb[nb - 3];
        pB4 = LD2(nb - 4); qB4 = PBb[nb - 4];
        pB5 = LD2(nb - 5); qB5 = PBb[nb - 5];
        pB6 = LD2(nb - 6); qB6 = PBb[nb - 6];
        pB7 = LD2(nb - 7); qB7 = PBb[nb - 7];   // at base=7: head pad rows
        SCHED_FENCE();
        BWD_STEP(base - 0, pA0, qA0)
        BWD_STEP(base - 1, pA1, qA1)
        BWD_STEP(base - 2, pA2, qA2)
        BWD_STEP(base - 3, pA3, qA3)
        BWD_STEP(base - 4, pA4, qA4)
        BWD_STEP(base - 5, pA5, qA5)
        BWD_STEP(base - 6, pA6, qA6)
        BWD_STEP(base - 7, pA7, qA7)
        SCHED_FENCE();
        PIN2(pB0); PIN2(pB1); PIN2(pB2); PIN2(pB3);
        PIN2(pB4); PIN2(pB5); PIN2(pB6); PIN2(pB7);
        PINF(qB0); PINF(qB1); PINF(qB2); PINF(qB3);
        PINF(qB4); PINF(qB5); PINF(qB6); PINF(qB7);
        pA0 = pB0; qA0 = qB0;  pA1 = pB1; qA1 = qB1;
        pA2 = pB2; qA2 = qB2;  pA3 = pB3; qA3 = qB3;
        pA4 = pB4; qA4 = qB4;  pA5 = pB5; qA5 = qB5;
        pA6 = pB6; qA6 = qB6;  pA7 = pB7; qA7 = qB7;
    }
}

// ---- loss step: consume named regs (no refill inside) ----------------------
#define LSTEP(tt, RA, RB, RP)                                                \
    {                                                                        \
        float a_nx = (RA), br_nx = (RB), p_nx = (RP);                        \
        float bl   = (a_t  == NEGINF) ? NEGINF : braw_t;                     \
        float term = (a_nx == NEGINF) ? NEGINF : (br_nx + p_nx);             \
        float bp = log_sub_expf(bl, term);                                   \
        float x = a_t + bp - 0.1f * (float)(tt) * inv_hl;                    \
        if (x != NEGINF) {                                                   \
            float nm = fmaxf(m, x);                                          \
            ssum = ssum * __expf(m - nm) + __expf(x - nm);                   \
            m = nm;                                                          \
        }                                                                    \
        a_t = a_nx; braw_t = br_nx;                                          \
    }

// ------------------- fused: fwd wave + bwd wave + 8-way loss ----------------
extern "C" __global__ void __launch_bounds__(1024, 4)
brctc_fused(const float* __restrict__ P, const float* __restrict__ PB,
            const int* __restrict__ ys, const int* __restrict__ hlens,
            const int* __restrict__ ylens,
            float* __restrict__ A, float* __restrict__ Braw,
            float* __restrict__ out)
{
    const int b = blockIdx.x;
    const int tid = threadIdx.x;
    const int w = tid >> 6;
    const int hl = hlens[b], yl = ylens[b];
    const size_t TP = T_DIM + 2 * PAD;
    const float* Pb  = P  + ((size_t)b * TP + PAD) * U_DIM;
    const float* PBb = PB + (size_t)b * TP + PAD;
    const int* ysb = ys + b * U_DIM;
    float* Ab = A    + (size_t)b * AROWS * U_DIM;
    float* Bb = Braw + (size_t)b * AROWS * U_DIM;

    if (w == 0)      fwd_scan5(Pb, PBb, ysb, hl, yl, Ab);
    else if (w == 1) bwd_scan5(Pb, PBb, ysb, hl, yl, Bb);
    __syncthreads();

    __shared__ float shm[8][U_DIM], shs[8][U_DIM], shlu[U_DIM];
    {
        const int u = tid & 127;
        const int c = tid >> 7;               // 0..7
        if (u < U_DIM) {
            const bool valu = (u < yl);       // p_l valid mask (s=2u+1 <= 2yl)
            const float inv_hl = 1.0f / (float)hl;
            const int t0 = 125 * c;
            float a_t    = Ab[(size_t)t0 * U_DIM + u];
            float braw_t = Bb[(size_t)t0 * U_DIM + u];
            float aA0 = Ab[(long)(t0 + 1) * U_DIM + u];
            float aA1 = Ab[(long)(t0 + 2) * U_DIM + u];
            float aA2 = Ab[(long)(t0 + 3) * U_DIM + u];
            float aA3 = Ab[(long)(t0 + 4) * U_DIM + u];
            float bA0 = Bb[(long)(t0 + 1) * U_DIM + u];
            float bA1 = Bb[(long)(t0 + 2) * U_DIM + u];
            float bA2 = Bb[(long)(t0 + 3) * U_DIM + u];
            float bA3 = Bb[(long)(t0 + 4) * U_DIM + u];
            float pA0 = valu ? Pb[(long)(t0 + 1) * U_DIM + u] : NEGINF;
            float pA1 = valu ? Pb[(long)(t0 + 2) * U_DIM + u] : NEGINF;
            float pA2 = valu ? Pb[(long)(t0 + 3) * U_DIM + u] : NEGINF;
            float pA3 = valu ? Pb[(long)(t0 + 4) * U_DIM + u] : NEGINF;
            float m = NEGINF, ssum = 0.0f;
            for (int kb = 0; kb <= 120; kb += 4) {     // 31 blocks: t0..t0+123
                long nr = (long)(t0 + kb + 5);
                float aB0 = Ab[(nr + 0) * U_DIM + u];
                float aB1 = Ab[(nr + 1) * U_DIM + u];
                float aB2 = Ab[(nr + 2) * U_DIM + u];
                float aB3 = Ab[(nr + 3) * U_DIM + u];
                float bB0 = Bb[(nr + 0) * U_DIM + u];
                float bB1 = Bb[(nr + 1) * U_DIM + u];
                float bB2 = Bb[(nr + 2) * U_DIM + u];
                float bB3 = Bb[(nr + 3) * U_DIM + u];
                float pB0 = valu ? Pb[(nr + 0) * U_DIM + u] : NEGINF;
                float pB1 = valu ? Pb[(nr + 1) * U_DIM + u] : NEGINF;
                float pB2 = valu ? Pb[(nr + 2) * U_DIM + u] : NEGINF;
                float pB3 = valu ? Pb[(nr + 3) * U_DIM + u] : NEGINF;
                SCHED_FENCE();
                LSTEP(t0 + kb + 0, aA0, bA0, pA0)
                LSTEP(t0 + kb + 1, aA1, bA1, pA1)
                LSTEP(t0 + kb + 2, aA2, bA2, pA2)
                LSTEP(t0 + kb + 3, aA3, bA3, pA3)
                SCHED_FENCE();
                PINF(aB0); PINF(aB1); PINF(aB2); PINF(aB3);
                PINF(bB0); PINF(bB1); PINF(bB2); PINF(bB3);
                PINF(pB0); PINF(pB1); PINF(pB2); PINF(pB3);
                aA0 = aB0; aA1 = aB1; aA2 = aB2; aA3 = aB3;
                bA0 = bB0; bA1 = bB1; bA2 = bB2; bA3 = bB3;
                pA0 = pB0; pA1 = pB1; pA2 = pB2; pA3 = pB3;
            }
            LSTEP(t0 + 124, aA0, bA0, pA0)             // 125th step
            shm[c][u] = m; shs[c][u] = ssum;
        }
    }
    __syncthreads();
    if (tid < U_DIM) {
        float M = NEGINF;
#pragma unroll
        for (int c = 0; c < 8; ++c) M = fmaxf(M, shm[c][tid]);
        float lu = NEGINF;
        if (M != NEGINF) {
            float s = 0.0f;
#pragma unroll
            for (int c = 0; c < 8; ++c) {
                float mc = shm[c][tid];
                if (mc != NEGINF) s += shs[c][tid] * __expf(mc - M);
            }
            lu = M + __logf(s);
        }
        shlu[tid] = lu;
    }
    __syncthreads();
    if (tid == 0) {
        int cnt = 0;
        for (int u = 0; u < U_DIM; ++u) cnt += (shlu[u] != NEGINF) ? 1 : 0;
        int last = cnt - 1;
        last = last < 0 ? 0 : (last > U_DIM - 1 ? U_DIM - 1 : last);
        out[b] = -shlu[last];
    }
}

// =================== fallback (small ws): round-1-style direct path =========
extern "C" __global__ void __launch_bounds__(256)
brctc_fwd_fb(const float* __restrict__ nnet, const int* __restrict__ ys,
             const int* __restrict__ hlens, const int* __restrict__ ylens,
             float* __restrict__ a_l)
{
    const int b = blockIdx.x;
    const int s = threadIdx.x;
    __shared__ float sh_a[201];
    __shared__ int   sh_ys[U_DIM];
    if (s < U_DIM) sh_ys[s] = ys[b * U_DIM + s];
    __syncthreads();
    const int hl = hlens[b], yl = ylens[b];
    int lab = 0; bool skip = false;
    if (s < 201) {
        if (s & 1) lab = sh_ys[(s - 1) >> 1];
        if ((s & 1) && s >= 3) skip = (sh_ys[(s - 1) >> 1] != sh_ys[(s - 3) >> 1]);
        sh_a[s] = (s == 0) ? 0.0f : NEGINF;
    }
    const bool valid = (s < 201) && (s <= 2 * yl);
    const bool isodd = (s < 201) && (s & 1);
    const int l = (s - 1) >> 1;
    const float* base = nnet + (size_t)b * T_DIM * C_DIM;
    float* alb = a_l + (size_t)b * T_DIM * U_DIM;
    __syncthreads();
    float p_cur = valid ? base[lab] : NEGINF;
    for (int t = 0; t < T_DIM; ++t) {
        float p_nxt = (valid && (t + 1 < T_DIM)) ? base[(size_t)(t + 1) * C_DIM + lab] : NEGINF;
        float x1 = (s < 201) ? sh_a[s] : NEGINF;
        float x2 = (s >= 1 && s < 201) ? sh_a[s - 1] : NEGINF;
        float x3 = skip ? sh_a[s - 2] : NEGINF;
        float anew = p_cur + lse3f(x1, x2, x3);
        __syncthreads();
        if (s < 201) sh_a[s] = anew;
        if (isodd) alb[t * U_DIM + l] = (t < hl) ? anew : NEGINF;
        __syncthreads();
        p_cur = p_nxt;
    }
}

extern "C" __global__ void __launch_bounds__(256)
brctc_bwd_fb(const float* __restrict__ nnet, const int* __restrict__ ys,
             const int* __restrict__ hlens, const int* __restrict__ ylens,
             const float* __restrict__ a_l, float* __restrict__ out)
{
    const int b = blockIdx.x;
    const int s = threadIdx.x;
    __shared__ float sh_b[201], sh_q[201], sh_lu[U_DIM];
    __shared__ int sh_ys[U_DIM];
    if (s < U_DIM) sh_ys[s] = ys[b * U_DIM + s];
    __syncthreads();
    const int hl = hlens[b], yl = ylens[b];
    int lab = 0; bool skip2 = false;
    if (s < 201) {
        if (s & 1) lab = sh_ys[(s - 1) >> 1];
        int s2 = s + 2;
        if (s2 < 201 && (s2 & 1) && s2 >= 3)
            skip2 = (sh_ys[(s2 - 1) >> 1] != sh_ys[(s2 - 3) >> 1]);
        sh_b[s] = NEGINF;
    }
    const bool valid = (s < 201) && (s <= 2 * yl);
    const bool isodd = (s < 201) && (s & 1);
    const int l = (s - 1) >> 1;
    const float fin0 = (s == 2 * yl || s == 2 * yl - 1) ? 0.0f : NEGINF;
    const float* base = nnet + (size_t)b * T_DIM * C_DIM;
    const float* alb = a_l + (size_t)b * T_DIM * U_DIM;
    float m_run = NEGINF, acc = 0.0f, prev_bl = NEGINF, p_hi = NEGINF;
    __syncthreads();
    for (int t = T_DIM - 1; t >= 0; --t) {
        float p_lo = valid ? base[(size_t)t * C_DIM + lab] : NEGINF;
        float a_cur = isodd ? alb[t * U_DIM + l] : NEGINF;
        float q = (s < 201) ? (p_hi + sh_b[s]) : NEGINF;
        if (s < 201) sh_q[s] = q;
        __syncthreads();
        float q2 = (s + 1 < 201) ? sh_q[s + 1] : NEGINF;
        float q3 = skip2 ? sh_q[s + 2] : NEGINF;
        float cand = lse3f(q, q2, q3);
        float bnew = (t == hl - 1) ? fin0 : cand;
        if (s < 201) sh_b[s] = bnew;
        if (isodd) {
            float bl_t = (a_cur == NEGINF) ? NEGINF : bnew;
            float bp = (t == T_DIM - 1) ? bl_t : log_sub_expf(bl_t, prev_bl + p_hi);
            float x = a_cur + bp - 0.1f * ((float)t / (float)hl);
            if (x != NEGINF) {
                if (x <= m_run) acc += __expf(x - m_run);
                else { acc = acc * __expf(m_run - x) + 1.0f; m_run = x; }
            }
            prev_bl = bl_t;
        }
        __syncthreads();
        p_hi = p_lo;
    }
    if (isodd) sh_lu[l] = (m_run == NEGINF) ? NEGINF : (m_run + __logf(acc));
    __syncthreads();
    if (s == 0) {
        int cnt = 0;
        for (int u = 0; u < U_DIM; ++u) cnt += (sh_lu[u] != NEGINF) ? 1 : 0;
        int last = cnt - 1;
        last = last < 0 ? 0 : (last > U_DIM - 1 ? U_DIM - 1 : last);
        out[b] = -sh_lu[last];
    }
}

extern "C" void kernel_launch(void* const* d_in, const int* in_sizes, int n_in,
                              void* d_out, int out_size, void* d_ws, size_t ws_size,
                              hipStream_t stream) {
    const float* nnet  = (const float*)d_in[0];
    const int*   ys    = (const int*)d_in[1];
    const int*   hlens = (const int*)d_in[2];
    const int*   ylens = (const int*)d_in[3];
    float*       outp  = (float*)d_out;
    const int B = in_sizes[2];
    const size_t TP = T_DIM + 2 * PAD;
    const size_t szP  = (size_t)B * TP * U_DIM;
    const size_t szPB = (size_t)B * TP;
    const size_t szA  = (size_t)B * AROWS * U_DIM;
    const size_t need = (szP + szPB + 2 * szA) * sizeof(float);

    if (ws_size >= need) {
        float* P    = (float*)d_ws;
        float* PB   = P + szP;
        float* A    = PB + szPB;
        float* Braw = A + szA;
        brctc_gather<<<dim3(T_DIM / 10, B), 256, 0, stream>>>(nnet, ys, P, PB);
        brctc_fused<<<B, 1024, 0, stream>>>(P, PB, ys, hlens, ylens, A, Braw, outp);
    } else {
        float* A = (float*)d_ws;
        brctc_fwd_fb<<<B, 256, 0, stream>>>(nnet, ys, hlens, ylens, A);
        brctc_bwd_fb<<<B, 256, 0, stream>>>(nnet, ys, hlens, ylens, A, outp);
    }
}

// Round 11
// 510.323 us; speedup vs baseline: 1.3754x; 1.0204x over previous
//
#include <hip/hip_runtime.h>
#include <math.h>

#define T_DIM 1000
#define C_DIM 500
#define U_DIM 100
#define PAD   16          // head/tail padding rows for P/PB
#define AROWS (T_DIM + 5) // A/Braw rows (loss pipeline reads to row T+4)
#define NEGINF (-INFINITY)

__device__ __forceinline__ float lse2f(float a, float b) {
    float m = fmaxf(a, b);
    if (m == NEGINF) return NEGINF;
    float mn = fminf(a, b);
    return m + __logf(1.0f + __expf(mn - m));
}

__device__ __forceinline__ float lse3f(float x1, float x2, float x3) {
    float m = fmaxf(fmaxf(x1, x2), x3);
    if (m == NEGINF) return NEGINF;
    return m + __logf(__expf(x1 - m) + __expf(x2 - m) + __expf(x3 - m));
}

// Bug-compatible replica of reference _log_sub_exp (incl. inf-substitution quirk).
__device__ __forceinline__ float log_sub_expf(float a, float b) {
    bool ia = isinf(a), ib = isinf(b);
    if (!ia && !ib) {
        float ans = b + __logf(__expf(a - b) - 1.0f);
        if (isinf(ans)) ans = -2001.0f + __logf(__expf(1.0f) - 1.0f);
        return ans;
    }
    if (!ia && ib) return a;
    return NEGINF;
}

// DPP lane shifts (validated bit-exact rounds 6-10)
__device__ __forceinline__ float dpp_shr1(float x) {  // lane L <- L-1; lane0 <- -inf
    int r = __builtin_amdgcn_update_dpp(__float_as_int(NEGINF), __float_as_int(x),
                                        0x138, 0xF, 0xF, false);  // wave_shr:1
    return __int_as_float(r);
}
__device__ __forceinline__ float dpp_shl1(float x) {  // lane L <- L+1; lane63 <- -inf
    int r = __builtin_amdgcn_update_dpp(__float_as_int(NEGINF), __float_as_int(x),
                                        0x130, 0xF, 0xF, false);  // wave_shl:1
    return __int_as_float(r);
}

// ---------- pre-gather: XCD-affine grid (blockIdx.x = batch), row-1000 = -inf
extern "C" __global__ void __launch_bounds__(256)
brctc_gather(const float* __restrict__ nnet, const int* __restrict__ ys,
             float* __restrict__ P, float* __restrict__ PB)
{
    const int b = blockIdx.x;                            // batch -> XCD b%8
    const int g = blockIdx.y * 2 + (threadIdx.x >> 7);   // 0..199
    const int l = threadIdx.x & 127;
    const int t0 = g * 5;
    const size_t TP = T_DIM + 2 * PAD;
    const float* rowb = nnet + ((size_t)b * T_DIM + t0) * C_DIM;
    if (l < U_DIM) {
        int lab = ys[b * U_DIM + l];
        float* Pr = P + ((size_t)b * TP + PAD + t0) * U_DIM;
#pragma unroll
        for (int i = 0; i < 5; ++i)
            Pr[(size_t)i * U_DIM + l] = rowb[(size_t)i * C_DIM + lab];
        if (t0 == 995) Pr[(size_t)5 * U_DIM + l] = NEGINF;   // row 1000
    } else if (l == U_DIM) {
        float* PBr = PB + (size_t)b * TP + PAD + t0;
#pragma unroll
        for (int i = 0; i < 5; ++i)
            PBr[i] = rowb[(size_t)i * C_DIM];
        if (t0 == 995) PBr[5] = NEGINF;                      // row 1000
    }
}

// ---- scan step macros (bit-identical formulas to r10) ----------------------
#define FWD_STEP(tt, PL, PBV)                                                \
    {                                                                        \
        float p0 = v0 ? (PBV)  : NEGINF;                                     \
        float p1 = v1 ? (PL).x : NEGINF;                                     \
        float p2 = v2 ? (PBV)  : NEGINF;                                     \
        float p3 = v3 ? (PL).y : NEGINF;                                     \
        float am1 = dpp_shr1(a3);                                            \
        float n0 = p0 + lse2f(a0, am1);                                      \
        float n1 = p1 + lse3f(a1, a0, skip1 ? am1 : NEGINF);                 \
        float n2 = p2 + lse2f(a2, a1);                                       \
        float n3 = p3 + lse3f(a3, a2, skip3 ? a1 : NEGINF);                  \
        a0 = n0; a1 = n1; a2 = n2; a3 = n3;                                  \
        if (st) {                                                            \
            bool live = ((tt) < hl);                                         \
            ((float2*)(Ab + (size_t)(tt) * U_DIM))[L] =                      \
                make_float2(live ? n1 : NEGINF, live ? n3 : NEGINF);         \
        }                                                                    \
    }

#define BWD_STEP(tt, PL, PBV)                                                \
    {                                                                        \
        float ph0 = v0 ? (PBV)  : NEGINF;                                    \
        float ph1 = v1 ? (PL).x : NEGINF;                                    \
        float ph2 = v2 ? (PBV)  : NEGINF;                                    \
        float ph3 = v3 ? (PL).y : NEGINF;                                    \
        float q0 = ph0 + b0, q1 = ph1 + b1, q2 = ph2 + b2, q3 = ph3 + b3;    \
        float qd0 = dpp_shl1(q0);                                            \
        float qd1 = dpp_shl1(q1);                                            \
        float n0 = lse2f(q0, q1);                                            \
        float n1 = lse3f(q1, q2, skipA ? q3 : NEGINF);                       \
        float n2 = lse2f(q2, q3);                                            \
        float n3 = lse3f(q3, qd0, skipB ? qd1 : NEGINF);                     \
        bool fin = ((tt) == hl - 1);                                         \
        b0 = fin ? f0 : n0;                                                  \
        b1 = fin ? f1 : n1;                                                  \
        b2 = fin ? f2 : n2;                                                  \
        b3 = fin ? f3 : n3;                                                  \
        if (st)                                                              \
            ((float2*)(Bb + (size_t)(tt) * U_DIM))[L] = make_float2(b1, b3); \
    }

// LDS float2 read: lane L of row rr (row stride 100 floats)
#define LDF(buf, rr) (((const float2*)((buf) + (rr) * 100))[L])

// ---- loss step (verbatim r10) ----------------------------------------------
#define LSTEP(tt, RA, RB, RP)                                                \
    {                                                                        \
        float a_nx = (RA), br_nx = (RB), p_nx = (RP);                        \
        float bl   = (a_t  == NEGINF) ? NEGINF : braw_t;                     \
        float term = (a_nx == NEGINF) ? NEGINF : (br_nx + p_nx);             \
        float bp = log_sub_expf(bl, term);                                   \
        float x = a_t + bp - 0.1f * (float)(tt) * inv_hl;                    \
        if (x != NEGINF) {                                                   \
            float nm = fmaxf(m, x);                                          \
            ssum = ssum * __expf(m - nm) + __expf(x - nm);                   \
            m = nm;                                                          \
        }                                                                    \
        a_t = a_nx; braw_t = br_nx;                                          \
    }

// ---- fused: LDS double-buffered chunks, loader waves feed 2 scanner waves --
extern "C" __global__ void __launch_bounds__(1024)
brctc_fused(const float* __restrict__ P, const float* __restrict__ PB,
            const int* __restrict__ ys, const int* __restrict__ hlens,
            const int* __restrict__ ylens,
            float* __restrict__ A, float* __restrict__ Braw,
            float* __restrict__ out)
{
    const int b = blockIdx.x;
    const int tid = threadIdx.x;
    const int w = tid >> 6, L = tid & 63;
    const int hl = hlens[b], yl = ylens[b];
    const size_t TP = T_DIM + 2 * PAD;
    const float* Pb  = P  + ((size_t)b * TP + PAD) * U_DIM;
    const float* PBb = PB + (size_t)b * TP + PAD;
    const int* ysb = ys + b * U_DIM;
    float* Ab = A    + (size_t)b * AROWS * U_DIM;
    float* Bb = Braw + (size_t)b * AROWS * U_DIM;

    // LDS: 2 dirs x 2 buffers x 50 rows x 100 floats (+ tail pad for lane>=50 reads)
    __shared__ __align__(16) float fbuf[2][5056];
    __shared__ __align__(16) float bbuf[2][5056];
    __shared__ float fpb[2][56], bpb[2][56];
    __shared__ float shm[8][U_DIM], shs[8][U_DIM], shlu[U_DIM];

    // ---- per-lane scan constants (computed by all threads, used by waves 0/1)
    const int s0_ = 4 * L, s1 = 4 * L + 1, s2_ = 4 * L + 2, s3 = 4 * L + 3;
    const int u1 = 2 * L;
    const int lab1 = ysb[min(u1, U_DIM - 1)];
    const int lab3 = ysb[min(u1 + 1, U_DIM - 1)];
    const int labm = ysb[min(max(u1 - 1, 0), U_DIM - 1)];
    const int labn = ysb[min(u1 + 2, U_DIM - 1)];
    const bool skip1 = (s1 >= 3) && (lab1 != labm);
    const bool skip3 = (lab3 != lab1);
    const bool skipA = (s1 < 199) && (lab3 != lab1);
    const bool skipB = (s3 < 199) && (labn != lab3);
    const int ty = 2 * yl;
    const bool v0 = (s0_ <= 200) && (s0_ <= ty);
    const bool v1 = (s1  <= 200) && (s1  <= ty);
    const bool v2 = (s2_ <= 200) && (s2_ <= ty);
    const bool v3 = (s3  <= 200) && (s3  <= ty);
    const bool st = (L < 50);
    const float f0 = (s0_ == ty || s0_ == ty - 1) ? 0.0f : NEGINF;
    const float f1 = (s1  == ty || s1  == ty - 1) ? 0.0f : NEGINF;
    const float f2 = (s2_ == ty || s2_ == ty - 1) ? 0.0f : NEGINF;
    const float f3 = (s3  == ty || s3  == ty - 1) ? 0.0f : NEGINF;

    float a0 = (L == 0) ? 0.0f : NEGINF, a1 = NEGINF, a2 = NEGINF, a3 = NEGINF;
    float b0 = NEGINF, b1 = NEGINF, b2 = NEGINF, b3 = NEGINF;

    // ---- prologue: fill fwd chunk 0 and bwd chunk 19 ----------------------
    if (w >= 2 && w < 9) {                 // fwd loaders (waves 2..8, 448 thr)
        int j = tid - 128;
        const float4* s4 = (const float4*)Pb;                  // rows 0..49
        float4* d4 = (float4*)fbuf[0];
        for (int i = j; i < 1250; i += 448) d4[i] = s4[i];
        if (j < 50) fpb[0][j] = PBb[j];
    } else if (w >= 9) {                   // bwd loaders (waves 9..15)
        int j = tid - 576;
        const float4* s4 = (const float4*)(Pb + 95100);        // rows 951..1000
        float4* d4 = (float4*)bbuf[0];
        for (int i = j; i < 1250; i += 448) d4[i] = s4[i];
        if (j < 50) bpb[0][j] = PBb[951 + j];
    }
    __syncthreads();

    // ---- 20 chunks of 50 steps --------------------------------------------
    for (int c = 0; c < 20; ++c) {
        if (w == 0) {                       // forward scan, chunk c
            const float* fb = fbuf[c & 1];
            const float* fp = fpb[c & 1];
            const int tb = 50 * c;
            for (int kk = 0; kk < 50; kk += 10) {
                float2 r0 = LDF(fb, kk + 0), r1 = LDF(fb, kk + 1);
                float2 r2 = LDF(fb, kk + 2), r3 = LDF(fb, kk + 3);
                float2 r4 = LDF(fb, kk + 4), r5 = LDF(fb, kk + 5);
                float2 r6 = LDF(fb, kk + 6), r7 = LDF(fb, kk + 7);
                float2 r8 = LDF(fb, kk + 8), r9 = LDF(fb, kk + 9);
                float g0 = fp[kk + 0], g1 = fp[kk + 1], g2 = fp[kk + 2];
                float g3 = fp[kk + 3], g4 = fp[kk + 4], g5 = fp[kk + 5];
                float g6 = fp[kk + 6], g7 = fp[kk + 7], g8 = fp[kk + 8];
                float g9 = fp[kk + 9];
                FWD_STEP(tb + kk + 0, r0, g0)
                FWD_STEP(tb + kk + 1, r1, g1)
                FWD_STEP(tb + kk + 2, r2, g2)
                FWD_STEP(tb + kk + 3, r3, g3)
                FWD_STEP(tb + kk + 4, r4, g4)
                FWD_STEP(tb + kk + 5, r5, g5)
                FWD_STEP(tb + kk + 6, r6, g6)
                FWD_STEP(tb + kk + 7, r7, g7)
                FWD_STEP(tb + kk + 8, r8, g8)
                FWD_STEP(tb + kk + 9, r9, g9)
            }
        } else if (w == 1) {                // backward scan, chunk 19-c
            const float* bbf = bbuf[c & 1];
            const float* bp  = bpb[c & 1];
            const int cc = 19 - c;
            const int tb = 50 * cc;         // steps tb+49 .. tb; slot = t - tb
            for (int kk = 49; kk >= 9; kk -= 10) {
                float2 r0 = LDF(bbf, kk - 0), r1 = LDF(bbf, kk - 1);
                float2 r2 = LDF(bbf, kk - 2), r3 = LDF(bbf, kk - 3);
                float2 r4 = LDF(bbf, kk - 4), r5 = LDF(bbf, kk - 5);
                float2 r6 = LDF(bbf, kk - 6), r7 = LDF(bbf, kk - 7);
                float2 r8 = LDF(bbf, kk - 8), r9 = LDF(bbf, kk - 9);
                float g0 = bp[kk - 0], g1 = bp[kk - 1], g2 = bp[kk - 2];
                float g3 = bp[kk - 3], g4 = bp[kk - 4], g5 = bp[kk - 5];
                float g6 = bp[kk - 6], g7 = bp[kk - 7], g8 = bp[kk - 8];
                float g9 = bp[kk - 9];
                BWD_STEP(tb + kk - 0, r0, g0)
                BWD_STEP(tb + kk - 1, r1, g1)
                BWD_STEP(tb + kk - 2, r2, g2)
                BWD_STEP(tb + kk - 3, r3, g3)
                BWD_STEP(tb + kk - 4, r4, g4)
                BWD_STEP(tb + kk - 5, r5, g5)
                BWD_STEP(tb + kk - 6, r6, g6)
                BWD_STEP(tb + kk - 7, r7, g7)
                BWD_STEP(tb + kk - 8, r8, g8)
                BWD_STEP(tb + kk - 9, r9, g9)
            }
        } else if (c < 19) {                // loaders: fill next buffers
            if (w < 9) {
                int j = tid - 128;
                const float4* s4 = (const float4*)(Pb + (size_t)(c + 1) * 5000);
                float4* d4 = (float4*)fbuf[(c + 1) & 1];
                for (int i = j; i < 1250; i += 448) d4[i] = s4[i];
                if (j < 50) fpb[(c + 1) & 1][j] = PBb[(c + 1) * 50 + j];
            } else {
                int j = tid - 576;
                int cc = 18 - c;            // next bwd chunk
                const float4* s4 = (const float4*)(Pb + (size_t)cc * 5000 + 100);
                float4* d4 = (float4*)bbuf[(c + 1) & 1];
                for (int i = j; i < 1250; i += 448) d4[i] = s4[i];
                if (j < 50) bpb[(c + 1) & 1][j] = PBb[cc * 50 + 1 + j];
            }
        }
        __syncthreads();
    }
    // sentinel row T = -inf (a_next at t = T-1 in loss phase)
    if (w == 0 && st)
        ((float2*)(Ab + (size_t)T_DIM * U_DIM))[L] = make_float2(NEGINF, NEGINF);
    __syncthreads();

    // ---- loss phase (verbatim r10 structure) ------------------------------
    {
        const int u = tid & 127;
        const int c = tid >> 7;               // 0..7
        if (u < U_DIM) {
            const bool valu = (u < yl);
            const float inv_hl = 1.0f / (float)hl;
            const int t0 = 125 * c;
            float a_t    = Ab[(size_t)t0 * U_DIM + u];
            float braw_t = Bb[(size_t)t0 * U_DIM + u];
            float aA0 = Ab[(long)(t0 + 1) * U_DIM + u];
            float aA1 = Ab[(long)(t0 + 2) * U_DIM + u];
            float aA2 = Ab[(long)(t0 + 3) * U_DIM + u];
            float aA3 = Ab[(long)(t0 + 4) * U_DIM + u];
            float bA0 = Bb[(long)(t0 + 1) * U_DIM + u];
            float bA1 = Bb[(long)(t0 + 2) * U_DIM + u];
            float bA2 = Bb[(long)(t0 + 3) * U_DIM + u];
            float bA3 = Bb[(long)(t0 + 4) * U_DIM + u];
            float pA0 = valu ? Pb[(long)(t0 + 1) * U_DIM + u] : NEGINF;
            float pA1 = valu ? Pb[(long)(t0 + 2) * U_DIM + u] : NEGINF;
            float pA2 = valu ? Pb[(long)(t0 + 3) * U_DIM + u] : NEGINF;
            float pA3 = valu ? Pb[(long)(t0 + 4) * U_DIM + u] : NEGINF;
            float m = NEGINF, ssum = 0.0f;
            for (int kb = 0; kb <= 120; kb += 4) {
                long nr = (long)(t0 + kb + 5);
                float aB0 = Ab[(nr + 0) * U_DIM + u];
                float aB1 = Ab[(nr + 1) * U_DIM + u];
                float aB2 = Ab[(nr + 2) * U_DIM + u];
                float aB3 = Ab[(nr + 3) * U_DIM + u];
                float bB0 = Bb[(nr + 0) * U_DIM + u];
                float bB1 = Bb[(nr + 1) * U_DIM + u];
                float bB2 = Bb[(nr + 2) * U_DIM + u];
                float bB3 = Bb[(nr + 3) * U_DIM + u];
                float pB0 = valu ? Pb[(nr + 0) * U_DIM + u] : NEGINF;
                float pB1 = valu ? Pb[(nr + 1) * U_DIM + u] : NEGINF;
                float pB2 = valu ? Pb[(nr + 2) * U_DIM + u] : NEGINF;
                float pB3 = valu ? Pb[(nr + 3) * U_DIM + u] : NEGINF;
                LSTEP(t0 + kb + 0, aA0, bA0, pA0)
                LSTEP(t0 + kb + 1, aA1, bA1, pA1)
                LSTEP(t0 + kb + 2, aA2, bA2, pA2)
                LSTEP(t0 + kb + 3, aA3, bA3, pA3)
                aA0 = aB0; aA1 = aB1; aA2 = aB2; aA3 = aB3;
                bA0 = bB0; bA1 = bB1; bA2 = bB2; bA3 = bB3;
                pA0 = pB0; pA1 = pB1; pA2 = pB2; pA3 = pB3;
            }
            LSTEP(t0 + 124, aA0, bA0, pA0)
            shm[c][u] = m; shs[c][u] = ssum;
        }
    }
    __syncthreads();
    if (tid < U_DIM) {
        float M = NEGINF;
#pragma unroll
        for (int c = 0; c < 8; ++c) M = fmaxf(M, shm[c][tid]);
        float lu = NEGINF;
        if (M != NEGINF) {
            float s = 0.0f;
#pragma unroll
            for (int c = 0; c < 8; ++c) {
                float mc = shm[c][tid];
                if (mc != NEGINF) s += shs[c][tid] * __expf(mc - M);
            }
            lu = M + __logf(s);
        }
        shlu[tid] = lu;
    }
    __syncthreads();
    if (tid == 0) {
        int cnt = 0;
        for (int u = 0; u < U_DIM; ++u) cnt += (shlu[u] != NEGINF) ? 1 : 0;
        int last = cnt - 1;
        last = last < 0 ? 0 : (last > U_DIM - 1 ? U_DIM - 1 : last);
        out[b] = -shlu[last];
    }
}

// =================== fallback (small ws): round-1-style direct path =========
extern "C" __global__ void __launch_bounds__(256)
brctc_fwd_fb(const float* __restrict__ nnet, const int* __restrict__ ys,
             const int* __restrict__ hlens, const int* __restrict__ ylens,
             float* __restrict__ a_l)
{
    const int b = blockIdx.x;
    const int s = threadIdx.x;
    __shared__ float sh_a[201];
    __shared__ int   sh_ys[U_DIM];
    if (s < U_DIM) sh_ys[s] = ys[b * U_DIM + s];
    __syncthreads();
    const int hl = hlens[b], yl = ylens[b];
    int lab = 0; bool skip = false;
    if (s < 201) {
        if (s & 1) lab = sh_ys[(s - 1) >> 1];
        if ((s & 1) && s >= 3) skip = (sh_ys[(s - 1) >> 1] != sh_ys[(s - 3) >> 1]);
        sh_a[s] = (s == 0) ? 0.0f : NEGINF;
    }
    const bool valid = (s < 201) && (s <= 2 * yl);
    const bool isodd = (s < 201) && (s & 1);
    const int l = (s - 1) >> 1;
    const float* base = nnet + (size_t)b * T_DIM * C_DIM;
    float* alb = a_l + (size_t)b * T_DIM * U_DIM;
    __syncthreads();
    float p_cur = valid ? base[lab] : NEGINF;
    for (int t = 0; t < T_DIM; ++t) {
        float p_nxt = (valid && (t + 1 < T_DIM)) ? base[(size_t)(t + 1) * C_DIM + lab] : NEGINF;
        float x1 = (s < 201) ? sh_a[s] : NEGINF;
        float x2 = (s >= 1 && s < 201) ? sh_a[s - 1] : NEGINF;
        float x3 = skip ? sh_a[s - 2] : NEGINF;
        float anew = p_cur + lse3f(x1, x2, x3);
        __syncthreads();
        if (s < 201) sh_a[s] = anew;
        if (isodd) alb[t * U_DIM + l] = (t < hl) ? anew : NEGINF;
        __syncthreads();
        p_cur = p_nxt;
    }
}

extern "C" __global__ void __launch_bounds__(256)
brctc_bwd_fb(const float* __restrict__ nnet, const int* __restrict__ ys,
             const int* __restrict__ hlens, const int* __restrict__ ylens,
             const float* __restrict__ a_l, float* __restrict__ out)
{
    const int b = blockIdx.x;
    const int s = threadIdx.x;
    __shared__ float sh_b[201], sh_q[201], sh_lu[U_DIM];
    __shared__ int sh_ys[U_DIM];
    if (s < U_DIM) sh_ys[s] = ys[b * U_DIM + s];
    __syncthreads();
    const int hl = hlens[b], yl = ylens[b];
    int lab = 0; bool skip2 = false;
    if (s < 201) {
        if (s & 1) lab = sh_ys[(s - 1) >> 1];
        int s2 = s + 2;
        if (s2 < 201 && (s2 & 1) && s2 >= 3)
            skip2 = (sh_ys[(s2 - 1) >> 1] != sh_ys[(s2 - 3) >> 1]);
        sh_b[s] = NEGINF;
    }
    const bool valid = (s < 201) && (s <= 2 * yl);
    const bool isodd = (s < 201) && (s & 1);
    const int l = (s - 1) >> 1;
    const float fin0 = (s == 2 * yl || s == 2 * yl - 1) ? 0.0f : NEGINF;
    const float* base = nnet + (size_t)b * T_DIM * C_DIM;
    const float* alb = a_l + (size_t)b * T_DIM * U_DIM;
    float m_run = NEGINF, acc = 0.0f, prev_bl = NEGINF, p_hi = NEGINF;
    __syncthreads();
    for (int t = T_DIM - 1; t >= 0; --t) {
        float p_lo = valid ? base[(size_t)t * C_DIM + lab] : NEGINF;
        float a_cur = isodd ? alb[t * U_DIM + l] : NEGINF;
        float q = (s < 201) ? (p_hi + sh_b[s]) : NEGINF;
        if (s < 201) sh_q[s] = q;
        __syncthreads();
        float q2 = (s + 1 < 201) ? sh_q[s + 1] : NEGINF;
        float q3 = skip2 ? sh_q[s + 2] : NEGINF;
        float cand = lse3f(q, q2, q3);
        float bnew = (t == hl - 1) ? fin0 : cand;
        if (s < 201) sh_b[s] = bnew;
        if (isodd) {
            float bl_t = (a_cur == NEGINF) ? NEGINF : bnew;
            float bp = (t == T_DIM - 1) ? bl_t : log_sub_expf(bl_t, prev_bl + p_hi);
            float x = a_cur + bp - 0.1f * ((float)t / (float)hl);
            if (x != NEGINF) {
                if (x <= m_run) acc += __expf(x - m_run);
                else { acc = acc * __expf(m_run - x) + 1.0f; m_run = x; }
            }
            prev_bl = bl_t;
        }
        __syncthreads();
        p_hi = p_lo;
    }
    if (isodd) sh_lu[l] = (m_run == NEGINF) ? NEGINF : (m_run + __logf(acc));
    __syncthreads();
    if (s == 0) {
        int cnt = 0;
        for (int u = 0; u < U_DIM; ++u) cnt += (sh_lu[u] != NEGINF) ? 1 : 0;
        int last = cnt - 1;
        last = last < 0 ? 0 : (last > U_DIM - 1 ? U_DIM - 1 : last);
        out[b] = -sh_lu[last];
    }
}

extern "C" void kernel_launch(void* const* d_in, const int* in_sizes, int n_in,
                              void* d_out, int out_size, void* d_ws, size_t ws_size,
                              hipStream_t stream) {
    const float* nnet  = (const float*)d_in[0];
    const int*   ys    = (const int*)d_in[1];
    const int*   hlens = (const int*)d_in[2];
    const int*   ylens = (const int*)d_in[3];
    float*       outp  = (float*)d_out;
    const int B = in_sizes[2];
    const size_t TP = T_DIM + 2 * PAD;
    const size_t szP  = (size_t)B * TP * U_DIM;
    const size_t szPB = (size_t)B * TP;
    const size_t szA  = (size_t)B * AROWS * U_DIM;
    const size_t need = (szP + szPB + 2 * szA) * sizeof(float);

    if (ws_size >= need) {
        float* P    = (float*)d_ws;
        float* PB   = P + szP;
        float* A    = PB + szPB;
        float* Braw = A + szA;
        brctc_gather<<<dim3(B, T_DIM / 10), 256, 0, stream>>>(nnet, ys, P, PB);
        brctc_fused<<<B, 1024, 0, stream>>>(P, PB, ys, hlens, ylens, A, Braw, outp);
    } else {
        float* A = (float*)d_ws;
        brctc_fwd_fb<<<B, 256, 0, stream>>>(nnet, ys, hlens, ylens, A);
        brctc_bwd_fb<<<B, 256, 0, stream>>>(nnet, ys, hlens, ylens, A, outp);
    }
}